// Round 1
// 241.553 us; speedup vs baseline: 1.0165x; 1.0165x over previous
//
#include <hip/hip_runtime.h>
#include <hip/hip_bf16.h>

#define NN 100000      // nodes
#define NE 200000      // edges (without self loops)
#define NT (NE + NN)   // total edges incl self loops
#define DIN 165
#define CHUNK 50000    // node chunk for agg/gemm2 (2 chunks)
#define PREPB 128
#define INITB 391
#define PACKB 8        // 2048 threads: kp in [0,32), c in [0,64)
#define W1PB 24        // W1 f16 [c][192] pack: 6144 u32
#define MISCGRID (PREPB + INITB + PACKB + W1PB)
#define NODEB 1563     // ceil(NN/64) blocks (64-node tiles)

typedef __attribute__((ext_vector_type(8))) short bf16x8_t;
typedef __attribute__((ext_vector_type(4))) float f32x4_t;
typedef _Float16 h2_t __attribute__((ext_vector_type(2)));
typedef _Float16 f16x8_t __attribute__((ext_vector_type(8)));

static __device__ __forceinline__ unsigned short f2bf(float f) {
    __hip_bfloat16 b = __float2bfloat16(f);
    return *(unsigned short*)&b;
}
static __device__ __forceinline__ float bfu(unsigned short u) {
    __hip_bfloat16 b = *(__hip_bfloat16*)&u;
    return __bfloat162float(b);
}
static __device__ __forceinline__ unsigned pkh2(float a, float b) {
    h2_t v; v[0] = (_Float16)a; v[1] = (_Float16)b;
    return *(unsigned*)&v;
}

// ---------------- merged: layer-2 prep (bf16 W2pT + wsd) | CSR init | mlp weight pack | W1 f16 pack ----------------

__global__ __launch_bounds__(256) void k_misc(const float* W2, const float* a2s, const float* a2d,
                                              float* wsd, __hip_bfloat16* W2pT,
                                              int* cnt, int* fill,
                                              const float* tsw1, const float* cw1,
                                              unsigned* tswp, unsigned* cwp,
                                              const float* W1, unsigned* W1pT) {
    int b = blockIdx.x;
    int tid = threadIdx.x;
    if (b < PREPB) {
        int i = b * 256 + tid;                 // [0, 32768)
        // W2pT[c][j] = bf16(W2[kk*512 + h*64 + c]),  j = h*64 + kk
        int c = i >> 9, j = i & 511;
        int hh = j >> 6, kk = j & 63;
        W2pT[i] = __float2bfloat16(W2[kk * 512 + hh * 64 + c]);
        if (i < 512) {
            int h = i >> 6, k = i & 63;
            float s = 0.f, d = 0.f;
            for (int cc = 0; cc < 64; cc++) {
                float w = W2[k * 512 + h * 64 + cc];
                s += w * a2s[h * 64 + cc];
                d += w * a2d[h * 64 + cc];
            }
            wsd[i] = s; wsd[512 + i] = d;
        }
    } else if (b < PREPB + INITB) {
        int i = (b - PREPB) * 256 + tid;
        if (i < NN) { cnt[i] = 0; fill[i] = 0; }
    } else if (b < PREPB + INITB + PACKB) {
        int i = (b - PREPB - INITB) * 256 + tid;  // [0, 2048): kp*64+c
        if (i < 2048) {
            int kp = i >> 6, c = i & 63;           // kp in [0,32)
            tswp[i] = pkh2(tsw1[(2 * kp) * 64 + c], tsw1[(2 * kp + 1) * 64 + c]);
            cwp[i]  = pkh2(cw1[(2 * kp) * 64 + c],  cw1[(2 * kp + 1) * 64 + c]);
        }
    } else {
        int i = (b - PREPB - INITB - PACKB) * 256 + tid;  // [0, 6144): c*96 + kp
        if (i < 6144) {
            int c = i / 96, kp = i - c * 96;
            int k = 2 * kp;
            float f0 = (k < DIN) ? W1[k * 64 + c] : 0.f;
            float f1 = (k + 1 < DIN) ? W1[(k + 1) * 64 + c] : 0.f;
            W1pT[i] = pkh2(f0, f1);               // [c][96] u32 = [c][192] f16, zero-padded K
        }
    }
}

// ---------------- CSR build ----------------

__global__ __launch_bounds__(256) void k_count(const int* dstE, int* cnt) {
    int e = blockIdx.x * 256 + threadIdx.x;
    if (e < NE) atomicAdd(&cnt[dstE[e]], 1);
}

// per-block inclusive scan of 1024 elements (256 thr x 4); +1 accounts the self loop
__global__ __launch_bounds__(256) void k_scanA(const int* cnt, int* rowptr, int* bsum) {
    __shared__ int sm[256];
    int t = threadIdx.x;
    int base = blockIdx.x * 1024;
    int v[4]; int s = 0;
    for (int i = 0; i < 4; i++) {
        int idx = base + t * 4 + i;
        v[i] = (idx < NN) ? (cnt[idx] + 1) : 0;
        s += v[i];
    }
    sm[t] = s; __syncthreads();
    for (int off = 1; off < 256; off <<= 1) {
        int x = (t >= off) ? sm[t - off] : 0;
        __syncthreads();
        sm[t] += x;
        __syncthreads();
    }
    int run = sm[t] - s;
    for (int i = 0; i < 4; i++) {
        run += v[i];
        int idx = base + t * 4 + i;
        if (idx < NN) rowptr[idx + 1] = run;
    }
    if (t == 255) bsum[blockIdx.x] = sm[255];
}

// exclusive scan of nb (<=128) block sums, one wave
__global__ __launch_bounds__(64) void k_scanB(int* bsum, int nb) {
    int lane = threadIdx.x;
    int v0 = (lane < nb) ? bsum[lane] : 0;
    int v1 = (64 + lane < nb) ? bsum[64 + lane] : 0;
    int s0 = v0;
    for (int off = 1; off < 64; off <<= 1) { int t = __shfl_up(s0, off); if (lane >= off) s0 += t; }
    int tot0 = __shfl(s0, 63);
    int s1 = v1;
    for (int off = 1; off < 64; off <<= 1) { int t = __shfl_up(s1, off); if (lane >= off) s1 += t; }
    if (lane < nb) bsum[lane] = s0 - v0;
    if (64 + lane < nb) bsum[64 + lane] = tot0 + s1 - v1;
}

__global__ __launch_bounds__(256) void k_scanC(const int* bsum, int* rowptr) {
    int i = blockIdx.x * 256 + threadIdx.x;
    if (i < NN) rowptr[i + 1] += bsum[i >> 10];
    if (i == 0) rowptr[0] = 0;
}

__global__ __launch_bounds__(256) void k_fill(const int* srcE, const int* dstE,
                                              const int* rowptr, int* fill, int* col, int* rowv) {
    int i = blockIdx.x * 256 + threadIdx.x;
    if (i >= NT) return;
    int s, d;
    if (i < NE) { s = srcE[i]; d = dstE[i]; }
    else        { s = i - NE; d = s; }        // self loop
    int p = rowptr[d] + atomicAdd(&fill[d], 1);
    col[p] = s;
    rowv[p] = d;
}

// ---------------- Layer 1 GEMM (f16 MFMA): 64 rows/block, 4 waves x 16 rows, K=165 pad 192 ----------------
// Per-wave-private LDS staging (no __syncthreads): stage 16x32 fp32 coalesced, cvt->f16 frags,
// B frags straight from L2 (W1pT f16 [c][192], shared by all blocks).

#define G1_LX(buf, s0)                                                          \
    _Pragma("unroll")                                                           \
    for (int i = 0; i < 8; i++) {                                               \
        int idx = l + i * 64;                                                   \
        int r = idx >> 5, kk = idx & 31;                                        \
        int n = n0 + r, k = (s0) * 32 + kk;                                     \
        buf[i] = (n < NN && k < DIN) ? x[(size_t)n * DIN + k] : 0.f;            \
    }

__global__ __launch_bounds__(256) void k_gemm1(const float* x, const unsigned* W1pT,
                                               const float* att_s, const float* att_d,
                                               __hip_bfloat16* h1b, float* aad1) {
    __shared__ float As[4][16 * 36];           // per-wave [16 rows][36] f32 (pad: 2-way max on b128 reads)
    int tid = threadIdx.x;
    int l = tid & 63, w = tid >> 6;
    int n0 = blockIdx.x * 64 + w * 16;         // this wave's 16 rows
    float* Aw = &As[w][0];
    int frow = l & 15;                         // A row / C col lane index
    int kg = l >> 4;                           // k-group 0..3 (8 k each)
    f32x4_t acc[4] = {};                       // 4 col-tiles of 16

    float xr[2][8];
    G1_LX(xr[0], 0)
    #pragma unroll
    for (int s = 0; s < 6; s++) {
        // stage current step's fp32 sub-tile (conflict-free: consecutive lanes -> consecutive kk)
        #pragma unroll
        for (int i = 0; i < 8; i++) {
            int idx = l + i * 64;
            Aw[(idx >> 5) * 36 + (idx & 31)] = xr[s & 1][i];
        }
        if (s < 5) { G1_LX(xr[(s + 1) & 1], s + 1) }   // issue next loads; they fly across the lgkm wait
        asm volatile("s_waitcnt lgkmcnt(0)" ::: "memory");  // wave-sync: own ds_writes landed
        float4 f0 = *(const float4*)&Aw[frow * 36 + kg * 8];
        float4 f1 = *(const float4*)&Aw[frow * 36 + kg * 8 + 4];
        f16x8_t av;
        av[0] = (_Float16)f0.x; av[1] = (_Float16)f0.y; av[2] = (_Float16)f0.z; av[3] = (_Float16)f0.w;
        av[4] = (_Float16)f1.x; av[5] = (_Float16)f1.y; av[6] = (_Float16)f1.z; av[7] = (_Float16)f1.w;
        #pragma unroll
        for (int t = 0; t < 4; t++) {
            uint4 bu = *(const uint4*)&W1pT[(t * 16 + frow) * 96 + s * 16 + kg * 4];
            acc[t] = __builtin_amdgcn_mfma_f32_16x16x32_f16(av, *(f16x8_t*)&bu, acc[t], 0, 0, 0);
        }
    }

    // epilogue: bf16 h1 rows + attention partials
    // C/D layout: col = l&15 (-> c = t*16+frow), row = kg*4 + q  [m89]
    unsigned short* h1u = (unsigned short*)h1b;
    float asv[4], adv[4];
    #pragma unroll
    for (int t = 0; t < 4; t++) {
        int c = t * 16 + frow;
        asv[t] = att_s[c]; adv[t] = att_d[c];
    }
    int hb = (l >> 3) & 1;                     // which head within the tile's pair
    #pragma unroll
    for (int q = 0; q < 4; q++) {
        int n = n0 + kg * 4 + q;
        bool ok = (n < NN);
        #pragma unroll
        for (int t = 0; t < 4; t++) {
            if (ok) h1u[(size_t)n * 64 + t * 16 + frow] = f2bf(acc[t][q]);
            float sv = acc[t][q] * asv[t];
            float dv = acc[t][q] * adv[t];
            sv += __shfl_xor(sv, 1); sv += __shfl_xor(sv, 2); sv += __shfl_xor(sv, 4);
            dv += __shfl_xor(dv, 1); dv += __shfl_xor(dv, 2); dv += __shfl_xor(dv, 4);
            if (ok && (l & 7) == 0) {
                int h = t * 2 + hb;            // 8-col head within 64 cols
                aad1[(size_t)n * 16 + h]     = sv;
                aad1[(size_t)n * 16 + 8 + h] = dv;
            }
        }
    }
}

// ---------------- per-edge softmax numerators (bf16): we[e][h] = exp(leaky(as[s][h]+ad[d][h])) ----------------

__global__ __launch_bounds__(256) void k_edgew(const float* aad, const int* col, const int* rowv,
                                               __hip_bfloat16* web) {
    int e = blockIdx.x * 256 + threadIdx.x;
    if (e >= NT) return;
    int s = col[e], d = rowv[e];
    float4 s0 = *(const float4*)&aad[(size_t)s * 16];
    float4 s1 = *(const float4*)&aad[(size_t)s * 16 + 4];
    float4 dd0 = *(const float4*)&aad[(size_t)d * 16 + 8];
    float4 dd1 = *(const float4*)&aad[(size_t)d * 16 + 12];
    float as[8] = {s0.x, s0.y, s0.z, s0.w, s1.x, s1.y, s1.z, s1.w};
    float ad[8] = {dd0.x, dd0.y, dd0.z, dd0.w, dd1.x, dd1.y, dd1.z, dd1.w};
    unsigned p[4];
    #pragma unroll
    for (int q = 0; q < 4; q++) {
        float a0 = as[2*q]   + ad[2*q];
        float a1 = as[2*q+1] + ad[2*q+1];
        a0 = a0 > 0.f ? a0 : 0.2f * a0;
        a1 = a1 > 0.f ? a1 : 0.2f * a1;
        p[q] = (unsigned)f2bf(__expf(a0)) | ((unsigned)f2bf(__expf(a1)) << 16);
    }
    *(uint4*)&web[(size_t)e * 8] = make_uint4(p[0], p[1], p[2], p[3]);
}

// ---------------- Layer-1 aggregation: pure weighted gather (bf16 everywhere) ----------------

__global__ __launch_bounds__(256) void k_agg1(const __hip_bfloat16* h1b, const __hip_bfloat16* we1b,
                                              const int* rowptr, const int* col,
                                              const float* b1, __hip_bfloat16* out1b) {
    int tid = threadIdx.x; int lane = tid & 63;
    int n = blockIdx.x * 4 + (tid >> 6);
    int h = lane >> 3;
    int rs = rowptr[n], re = rowptr[n + 1];
    float den = 0.f, acc = 0.f;
    int sN = col[rs];                        // deg >= 1 (self loop)
    for (int e = rs; e < re; e++) {
        int s = sN;
        sN = (e + 1 < re) ? col[e + 1] : 0;  // prefetch next col
        float w = __bfloat162float(we1b[(size_t)e * 8 + h]);  // broadcast per 8 lanes
        den += w;
        acc += w * __bfloat162float(h1b[(size_t)s * 64 + lane]);
    }
    out1b[(size_t)n * 64 + lane] = __float2bfloat16(acc / (den + 1e-16f) + b1[lane]);
}

// ---------------- layer-2 logits: aad2[n][j] = <out1[n], wsd[j]>, LDS-staged GEMV ----------------

__global__ __launch_bounds__(256) void k_att2(const __hip_bfloat16* out1b, const float* wsd,
                                              float* aad2) {
    __shared__ float t[64][65];
    int tid = threadIdx.x;
    int n0 = blockIdx.x * 64;
    const unsigned short* o1u = (const unsigned short*)out1b;
    #pragma unroll
    for (int l = 0; l < 4; l++) {
        int q = tid + l * 256;               // 1024 chunks of 4 bf16 in the 64x64 tile
        int r = q >> 4, c4 = q & 15;
        int n = n0 + r;
        uint2 v = make_uint2(0, 0);
        if (n < NN) v = *(const uint2*)&o1u[(size_t)n * 64 + c4 * 4];
        t[r][c4 * 4 + 0] = bfu((unsigned short)(v.x & 0xffff));
        t[r][c4 * 4 + 1] = bfu((unsigned short)(v.x >> 16));
        t[r][c4 * 4 + 2] = bfu((unsigned short)(v.y & 0xffff));
        t[r][c4 * 4 + 3] = bfu((unsigned short)(v.y >> 16));
    }
    __syncthreads();
    int lane = tid & 63;
    int j0 = __builtin_amdgcn_readfirstlane((tid >> 6) * 4);   // wave-uniform -> scalar wsd loads
    int n = n0 + lane;
    float a0 = 0.f, a1 = 0.f, a2 = 0.f, a3 = 0.f;
    #pragma unroll 8
    for (int k = 0; k < 64; k++) {
        float ov = t[lane][k];               // (lane+k)%32 banks: 2-way, free
        a0 += ov * wsd[(j0 + 0) * 64 + k];
        a1 += ov * wsd[(j0 + 1) * 64 + k];
        a2 += ov * wsd[(j0 + 2) * 64 + k];
        a3 += ov * wsd[(j0 + 3) * 64 + k];
    }
    if (n < NN) *(float4*)&aad2[(size_t)n * 16 + j0] = make_float4(a0, a1, a2, a3);
}

// ---------------- Layer-2 aggregation (8 heads, bf16 weights) -> bf16 agg ----------------

__global__ __launch_bounds__(256) void k_agg2(const __hip_bfloat16* out1b, const __hip_bfloat16* we2b,
                                              const int* rowptr, const int* col,
                                              __hip_bfloat16* aggb, int n0, int n1) {
    int tid = threadIdx.x; int lane = tid & 63;
    int n = n0 + blockIdx.x * 4 + (tid >> 6);
    if (n >= n1) return;
    int rs = rowptr[n], re = rowptr[n + 1];
    float den[8] = {}, acc[8] = {};
    const unsigned short* weu = (const unsigned short*)we2b;
    int sN = col[rs];
    for (int e = rs; e < re; e++) {
        int s = sN;
        sN = (e + 1 < re) ? col[e + 1] : 0;  // prefetch next col
        uint4 wv = *(const uint4*)&weu[(size_t)e * 8];        // uniform addr -> broadcast
        float hv = __bfloat162float(out1b[(size_t)s * 64 + lane]);
        float w[8] = {bfu((unsigned short)(wv.x & 0xffff)), bfu((unsigned short)(wv.x >> 16)),
                      bfu((unsigned short)(wv.y & 0xffff)), bfu((unsigned short)(wv.y >> 16)),
                      bfu((unsigned short)(wv.z & 0xffff)), bfu((unsigned short)(wv.z >> 16)),
                      bfu((unsigned short)(wv.w & 0xffff)), bfu((unsigned short)(wv.w >> 16))};
        #pragma unroll
        for (int hh = 0; hh < 8; hh++) {
            den[hh] += w[hh];
            acc[hh] += w[hh] * hv;
        }
    }
    size_t base = (size_t)(n - n0) * 512;
    #pragma unroll
    for (int hh = 0; hh < 8; hh++)
        aggb[base + hh * 64 + lane] = __float2bfloat16(acc[hh] / (den[hh] + 1e-16f));
}

// ---------------- gemm2 (bf16 MFMA): out2Tb[c][n] = bf16(0.125 * aggb[n] @ W2pT[c]^T + b2[c]) ----------------

__global__ __launch_bounds__(256) void k_gemm2(const __hip_bfloat16* aggb, const __hip_bfloat16* W2pT,
                                               const float* b2, __hip_bfloat16* out2Tb, int n0, int n1) {
    __shared__ float smem[4608];               // 18432 B: A_lds 64x72 bf16 | B_lds 64x72 bf16; reused as [64][66] f32
    unsigned short* A_lds = (unsigned short*)smem;           // [64][72] bf16, row 144 B
    unsigned short* B_lds = A_lds + 64 * 72;                 // [64][72] bf16
    const unsigned short* A_g = (const unsigned short*)aggb;
    const unsigned short* B_g = (const unsigned short*)W2pT;
    int tid = threadIdx.x;
    int w = tid >> 6, l = tid & 63;
    int m0 = blockIdx.x * 64;
    int rows = n1 - n0;
    f32x4_t acc[4] = {};                       // 4 col-tiles for this wave's 16-row band
    for (int k0 = 0; k0 < 512; k0 += 64) {
        #pragma unroll
        for (int ll = 0; ll < 2; ll++) {
            int u = tid + ll * 256;            // [0,512): r = row/col (64), seg = 8x8 bf16
            int r = u >> 3, seg = u & 7;
            uint4 va = make_uint4(0, 0, 0, 0);
            if (m0 + r < rows) va = *(const uint4*)&A_g[(size_t)(m0 + r) * 512 + k0 + seg * 8];
            *(uint4*)&A_lds[r * 72 + seg * 8] = va;
            *(uint4*)&B_lds[r * 72 + seg * 8] = *(const uint4*)&B_g[(size_t)r * 512 + k0 + seg * 8];
        }
        __syncthreads();
        #pragma unroll
        for (int kk = 0; kk < 2; kk++) {
            bf16x8_t a = *(const bf16x8_t*)&A_lds[(w * 16 + (l & 15)) * 72 + kk * 32 + (l >> 4) * 8];
            #pragma unroll
            for (int t = 0; t < 4; t++) {
                bf16x8_t bb = *(const bf16x8_t*)&B_lds[(t * 16 + (l & 15)) * 72 + kk * 32 + (l >> 4) * 8];
                acc[t] = __builtin_amdgcn_mfma_f32_16x16x32_bf16(a, bb, acc[t], 0, 0, 0);
            }
        }
        __syncthreads();
    }
    // epilogue: scale+bias into LDS f32 bounce, then coalesced transposed bf16 store
    #pragma unroll
    for (int t = 0; t < 4; t++) {
        int col_l = l & 15;
        float bias = b2[t * 16 + col_l];
        #pragma unroll
        for (int q = 0; q < 4; q++) {
            int row_l = (l >> 4) * 4 + q;      // C/D: col=lane&15, row=(lane>>4)*4+reg [m89]
            smem[(w * 16 + row_l) * 66 + t * 16 + col_l] = 0.125f * acc[t][q] + bias;
        }
    }
    __syncthreads();
    unsigned short* o2u = (unsigned short*)out2Tb;
    int ml = tid & 63, cr = tid >> 6;
    #pragma unroll
    for (int p = 0; p < 16; p++) {
        int c = p * 4 + cr;
        int gr = m0 + ml;
        if (gr < rows) o2u[(size_t)c * NN + (n0 + gr)] = f2bf(smem[ml * 66 + c]);
    }
}

// ---------------- MLP heads + CE: packed-h2 o tile in LDS, dot2 inner, 16+16 accumulators ----------------

__global__ __launch_bounds__(256) void k_mlp(const __hip_bfloat16* out2Tb,
                                             const unsigned* tswp, const float* tsb1,
                                             const float* tsw2, const float* tsb2,
                                             const unsigned* cwp, const float* cb1,
                                             const float* cw2, const float* cb2,
                                             const int* tst, const int* ctg, const unsigned char* msk,
                                             float* part) {
    __shared__ unsigned t2h[32 * 64];          // [kp][node_local] packed half2 (o[2kp], o[2kp+1])
    __shared__ float red[4][7][64];
    int tid = threadIdx.x;
    int lane = tid & 63;
    int w = tid >> 6;
    int n0 = blockIdx.x * 64;
    int nstage = n0 + lane; if (nstage >= NN) nstage = NN - 1;
    const unsigned short* o2u = (const unsigned short*)out2Tb;
    #pragma unroll
    for (int l = 0; l < 8; l++) {
        int kp = w * 8 + l;
        float e0 = bfu(o2u[(size_t)(2 * kp) * NN + nstage]);       // coalesced
        float e1 = bfu(o2u[(size_t)(2 * kp + 1) * NN + nstage]);
        t2h[kp * 64 + lane] = pkh2(e0, e1);
    }
    __syncthreads();

    int c0 = __builtin_amdgcn_readfirstlane(w * 16);          // wave-uniform -> scalar weight loads
    int n = n0 + lane;
    float vts[16], vcls[16];
    #pragma unroll
    for (int j = 0; j < 16; j++) { vts[j] = tsb1[c0 + j]; vcls[j] = cb1[c0 + j]; }
    for (int kp = 0; kp < 32; kp++) {
        unsigned ou = t2h[kp * 64 + lane];                    // conflict-free (stride 64, 1 row)
        h2_t ov = *(h2_t*)&ou;
        const unsigned* wt = &tswp[kp * 64 + c0];             // wave-uniform -> s_load_dwordx4
        const unsigned* wc = &cwp[kp * 64 + c0];
        #pragma unroll
        for (int j = 0; j < 16; j++) {
            unsigned wtv = wt[j], wcv = wc[j];
            vts[j]  = __builtin_amdgcn_fdot2(ov, *(h2_t*)&wtv, vts[j], false);
            vcls[j] = __builtin_amdgcn_fdot2(ov, *(h2_t*)&wcv, vcls[j], false);
        }
    }
    float lg[5] = {0.f, 0.f, 0.f, 0.f, 0.f};
    float lg2[2] = {0.f, 0.f};
    #pragma unroll
    for (int j = 0; j < 16; j++) {
        int c = c0 + j;
        float v = fmaxf(vts[j], 0.f);
        #pragma unroll
        for (int t = 0; t < 5; t++) lg[t] += v * tsw2[c * 5 + t];
        float v2 = fmaxf(vcls[j], 0.f);
        lg2[0] += v2 * cw2[c * 2];
        lg2[1] += v2 * cw2[c * 2 + 1];
    }
    #pragma unroll
    for (int t = 0; t < 5; t++) red[w][t][lane] = lg[t];
    red[w][5][lane] = lg2[0];
    red[w][6][lane] = lg2[1];
    __syncthreads();
    if (w == 0) {
        float tsl = 0.f, cll = 0.f, mval = 0.f;
        if (n < NN) {
            float L[5];
            #pragma unroll
            for (int t = 0; t < 5; t++)
                L[t] = red[0][t][lane] + red[1][t][lane] + red[2][t][lane] + red[3][t][lane] + tsb2[t];
            float mx = L[0];
            #pragma unroll
            for (int t = 1; t < 5; t++) mx = fmaxf(mx, L[t]);
            float se = 0.f;
            #pragma unroll
            for (int t = 0; t < 5; t++) se += __expf(L[t] - mx);
            int tg = tst[n];
            float pick = 0.f;
            #pragma unroll
            for (int t = 0; t < 5; t++) pick += (t == tg) ? L[t] : 0.f;
            tsl = mx + __logf(se) - pick;
            float C0 = red[0][5][lane] + red[1][5][lane] + red[2][5][lane] + red[3][5][lane] + cb2[0];
            float C1 = red[0][6][lane] + red[1][6][lane] + red[2][6][lane] + red[3][6][lane] + cb2[1];
            float mx2 = fmaxf(C0, C1);
            float lse2 = mx2 + __logf(__expf(C0 - mx2) + __expf(C1 - mx2));
            mval = msk[n] ? 1.f : 0.f;
            float pick2 = ctg[n] ? C1 : C0;
            cll = (lse2 - pick2) * mval;
        }
        #pragma unroll
        for (int off = 1; off < 64; off <<= 1) {
            tsl  += __shfl_xor(tsl, off);
            cll  += __shfl_xor(cll, off);
            mval += __shfl_xor(mval, off);
        }
        if (lane == 0) {
            part[blockIdx.x * 3 + 0] = tsl;
            part[blockIdx.x * 3 + 1] = cll;
            part[blockIdx.x * 3 + 2] = mval;
        }
    }
}

__global__ __launch_bounds__(256) void k_final(const float* part, float* out, int nb) {
    __shared__ float sm[3][256];
    int tid = threadIdx.x;
    float a = 0, b = 0, c = 0;
    for (int i = tid; i < nb; i += 256) { a += part[i*3]; b += part[i*3+1]; c += part[i*3+2]; }
    sm[0][tid] = a; sm[1][tid] = b; sm[2][tid] = c;
    __syncthreads();
    for (int s = 128; s > 0; s >>= 1) {
        if (tid < s) {
            sm[0][tid] += sm[0][tid + s];
            sm[1][tid] += sm[1][tid + s];
            sm[2][tid] += sm[2][tid + s];
        }
        __syncthreads();
    }
    if (tid == 0) out[0] = sm[1][0] / sm[2][0] + sm[0][0] / (float)NN;
}

// ---------------- host ----------------

extern "C" void kernel_launch(void* const* d_in, const int* in_sizes, int n_in,
                              void* d_out, int out_size, void* d_ws, size_t ws_size,
                              hipStream_t stream) {
    const float* x    = (const float*)d_in[0];
    const int*   ei   = (const int*)d_in[1];
    const int*   tst  = (const int*)d_in[2];
    const int*   ctg  = (const int*)d_in[3];
    const unsigned char* msk = (const unsigned char*)d_in[4];
    const float* W1   = (const float*)d_in[5];
    const float* a1s  = (const float*)d_in[6];
    const float* a1d  = (const float*)d_in[7];
    const float* b1   = (const float*)d_in[8];
    const float* W2   = (const float*)d_in[9];
    const float* a2s  = (const float*)d_in[10];
    const float* a2d  = (const float*)d_in[11];
    const float* b2   = (const float*)d_in[12];
    const float* tsw1 = (const float*)d_in[13];
    const float* tsb1 = (const float*)d_in[14];
    const float* tsw2 = (const float*)d_in[15];
    const float* tsb2 = (const float*)d_in[16];
    const float* cw1  = (const float*)d_in[17];
    const float* cb1  = (const float*)d_in[18];
    const float* cw2  = (const float*)d_in[19];
    const float* cb2  = (const float*)d_in[20];
    const int* srcE = ei;
    const int* dstE = ei + NE;

    char* ws = (char*)d_ws;
    size_t off = 0;
    auto alloc = [&](size_t b) { size_t o = off; off = (off + b + 255) & ~(size_t)255; return o; };
    int*   cnt    = (int*)(ws + alloc((size_t)NN * 4));
    int*   fill   = (int*)(ws + alloc((size_t)NN * 4));
    int*   rowptr = (int*)(ws + alloc((size_t)(NN + 1) * 4));
    int*   bsum   = (int*)(ws + alloc(128 * 4));
    int*   col    = (int*)(ws + alloc((size_t)NT * 4));
    int*   rowv   = (int*)(ws + alloc((size_t)NT * 4));
    float* aad1   = (float*)(ws + alloc((size_t)NN * 16 * 4));
    __hip_bfloat16* out1b = (__hip_bfloat16*)(ws + alloc((size_t)NN * 64 * 2));
    float* aad2   = (float*)(ws + alloc((size_t)NN * 16 * 4));
    float* wsd    = (float*)(ws + alloc(1024 * 4));
    __hip_bfloat16* W2pT  = (__hip_bfloat16*)(ws + alloc(32768 * 2));
    unsigned* tswp = (unsigned*)(ws + alloc(2048 * 4));
    unsigned* cwp  = (unsigned*)(ws + alloc(2048 * 4));
    unsigned* W1pT = (unsigned*)(ws + alloc(6144 * 4));
    __hip_bfloat16* out2Tb = (__hip_bfloat16*)(ws + alloc((size_t)NN * 64 * 2));
    __hip_bfloat16* h1b   = (__hip_bfloat16*)(ws + alloc((size_t)NN * 64 * 2));
    __hip_bfloat16* aggb  = (__hip_bfloat16*)(ws + alloc((size_t)CHUNK * 512 * 2));
    __hip_bfloat16* web   = (__hip_bfloat16*)(ws + alloc((size_t)NT * 8 * 2));
    float* part   = (float*)(ws + alloc((size_t)NODEB * 3 * 4));
    (void)ws_size; (void)in_sizes; (void)n_in; (void)out_size;

    int nb_scan = (NN + 1023) / 1024;  // 98

    k_misc<<<MISCGRID, 256, 0, stream>>>(W2, a2s, a2d, wsd, W2pT, cnt, fill,
                                         tsw1, cw1, tswp, cwp, W1, W1pT);
    k_count<<<(NE + 255) / 256, 256, 0, stream>>>(dstE, cnt);
    k_scanA<<<nb_scan, 256, 0, stream>>>(cnt, rowptr, bsum);
    k_scanB<<<1, 64, 0, stream>>>(bsum, nb_scan);
    k_scanC<<<(NN + 255) / 256, 256, 0, stream>>>(bsum, rowptr);
    k_fill<<<(NT + 255) / 256, 256, 0, stream>>>(srcE, dstE, rowptr, fill, col, rowv);

    k_gemm1<<<NODEB, 256, 0, stream>>>(x, W1pT, a1s, a1d, h1b, aad1);
    k_edgew<<<(NT + 255) / 256, 256, 0, stream>>>(aad1, col, rowv, web);
    k_agg1<<<NN / 4, 256, 0, stream>>>(h1b, web, rowptr, col, b1, out1b);
    k_att2<<<NODEB, 256, 0, stream>>>(out1b, wsd, aad2);
    k_edgew<<<(NT + 255) / 256, 256, 0, stream>>>(aad2, col, rowv, web);

    for (int c = 0; c < 2; c++) {
        int n0 = c * CHUNK, n1 = n0 + CHUNK;
        k_agg2<<<CHUNK / 4, 256, 0, stream>>>(out1b, web, rowptr, col, aggb, n0, n1);
        k_gemm2<<<(CHUNK + 63) / 64, 256, 0, stream>>>(aggb, W2pT, b2, out2Tb, n0, n1);
    }

    k_mlp<<<NODEB, 256, 0, stream>>>(out2Tb, tswp, tsb1, tsw2, tsb2,
                                     cwp, cb1, cw2, cb2, tst, ctg, msk, part);
    k_final<<<1, 256, 0, stream>>>(part, (float*)d_out, NODEB);
}

// Round 2
// 214.157 us; speedup vs baseline: 1.1465x; 1.1279x over previous
//
#include <hip/hip_runtime.h>
#include <hip/hip_bf16.h>

#define NN 100000      // nodes
#define NE 200000      // edges (without self loops)
#define NT (NE + NN)   // total edges incl self loops
#define DIN 165
#define CHUNK 50000    // node chunk for agg/gemm2 (2 chunks)
#define PREPB 128
#define INITB 391
#define PACKB 8        // 2048 threads: kp in [0,32), c in [0,64)
#define W1PB 24        // W1 f16 [c][192] pack: 6144 u32
#define MISCGRID (PREPB + INITB + PACKB + W1PB)
#define NODEB 1563     // ceil(NN/64) blocks (64-node tiles)

typedef __attribute__((ext_vector_type(8))) short bf16x8_t;
typedef __attribute__((ext_vector_type(4))) float f32x4_t;
typedef _Float16 h2_t __attribute__((ext_vector_type(2)));
typedef _Float16 f16x8_t __attribute__((ext_vector_type(8)));

#define AS1 __attribute__((address_space(1)))
#define AS3 __attribute__((address_space(3)))

static __device__ __forceinline__ unsigned short f2bf(float f) {
    __hip_bfloat16 b = __float2bfloat16(f);
    return *(unsigned short*)&b;
}
static __device__ __forceinline__ float bfu(unsigned short u) {
    __hip_bfloat16 b = *(__hip_bfloat16*)&u;
    return __bfloat162float(b);
}
static __device__ __forceinline__ unsigned pkh2(float a, float b) {
    h2_t v; v[0] = (_Float16)a; v[1] = (_Float16)b;
    return *(unsigned*)&v;
}

// ---------------- merged: layer-2 prep (bf16 W2pT + wsd) | CSR init | mlp weight pack | W1 f16 pack ----------------

__global__ __launch_bounds__(256) void k_misc(const float* W2, const float* a2s, const float* a2d,
                                              float* wsd, __hip_bfloat16* W2pT,
                                              int* cnt, int* fill,
                                              const float* tsw1, const float* cw1,
                                              unsigned* tswp, unsigned* cwp,
                                              const float* W1, unsigned* W1pT, float* zbuf) {
    int b = blockIdx.x;
    int tid = threadIdx.x;
    if (b < PREPB) {
        int i = b * 256 + tid;                 // [0, 32768)
        // W2pT[c][j] = bf16(W2[kk*512 + h*64 + c]),  j = h*64 + kk
        int c = i >> 9, j = i & 511;
        int hh = j >> 6, kk = j & 63;
        W2pT[i] = __float2bfloat16(W2[kk * 512 + hh * 64 + c]);
        if (b == 0 && tid < 64) zbuf[tid] = 0.f;   // zero source for gemm1 DMA padding
        if (i < 512) {
            int h = i >> 6, k = i & 63;
            float s = 0.f, d = 0.f;
            for (int cc = 0; cc < 64; cc++) {
                float w = W2[k * 512 + h * 64 + cc];
                s += w * a2s[h * 64 + cc];
                d += w * a2d[h * 64 + cc];
            }
            wsd[i] = s; wsd[512 + i] = d;
        }
    } else if (b < PREPB + INITB) {
        int i = (b - PREPB) * 256 + tid;
        if (i < NN) { cnt[i] = 0; fill[i] = 0; }
    } else if (b < PREPB + INITB + PACKB) {
        int i = (b - PREPB - INITB) * 256 + tid;  // [0, 2048): kp*64+c
        if (i < 2048) {
            int kp = i >> 6, c = i & 63;           // kp in [0,32)
            tswp[i] = pkh2(tsw1[(2 * kp) * 64 + c], tsw1[(2 * kp + 1) * 64 + c]);
            cwp[i]  = pkh2(cw1[(2 * kp) * 64 + c],  cw1[(2 * kp + 1) * 64 + c]);
        }
    } else {
        int i = (b - PREPB - INITB - PACKB) * 256 + tid;  // [0, 6144): c*96 + kp
        if (i < 6144) {
            int c = i / 96, kp = i - c * 96;
            int k = 2 * kp;
            float f0 = (k < DIN) ? W1[k * 64 + c] : 0.f;
            float f1 = (k + 1 < DIN) ? W1[(k + 1) * 64 + c] : 0.f;
            W1pT[i] = pkh2(f0, f1);               // [c][96] u32 = [c][192] f16, zero-padded K
        }
    }
}

// ---------------- CSR build ----------------

__global__ __launch_bounds__(256) void k_count(const int* dstE, int* cnt) {
    int e = blockIdx.x * 256 + threadIdx.x;
    if (e < NE) atomicAdd(&cnt[dstE[e]], 1);
}

// per-block inclusive scan of 1024 elements (256 thr x 4); +1 accounts the self loop
__global__ __launch_bounds__(256) void k_scanA(const int* cnt, int* rowptr, int* bsum) {
    __shared__ int sm[256];
    int t = threadIdx.x;
    int base = blockIdx.x * 1024;
    int v[4]; int s = 0;
    for (int i = 0; i < 4; i++) {
        int idx = base + t * 4 + i;
        v[i] = (idx < NN) ? (cnt[idx] + 1) : 0;
        s += v[i];
    }
    sm[t] = s; __syncthreads();
    for (int off = 1; off < 256; off <<= 1) {
        int x = (t >= off) ? sm[t - off] : 0;
        __syncthreads();
        sm[t] += x;
        __syncthreads();
    }
    int run = sm[t] - s;
    for (int i = 0; i < 4; i++) {
        run += v[i];
        int idx = base + t * 4 + i;
        if (idx < NN) rowptr[idx + 1] = run;
    }
    if (t == 255) bsum[blockIdx.x] = sm[255];
}

// exclusive scan of nb (<=128) block sums, one wave
__global__ __launch_bounds__(64) void k_scanB(int* bsum, int nb) {
    int lane = threadIdx.x;
    int v0 = (lane < nb) ? bsum[lane] : 0;
    int v1 = (64 + lane < nb) ? bsum[64 + lane] : 0;
    int s0 = v0;
    for (int off = 1; off < 64; off <<= 1) { int t = __shfl_up(s0, off); if (lane >= off) s0 += t; }
    int tot0 = __shfl(s0, 63);
    int s1 = v1;
    for (int off = 1; off < 64; off <<= 1) { int t = __shfl_up(s1, off); if (lane >= off) s1 += t; }
    if (lane < nb) bsum[lane] = s0 - v0;
    if (64 + lane < nb) bsum[64 + lane] = tot0 + s1 - v1;
}

__global__ __launch_bounds__(256) void k_scanC(const int* bsum, int* rowptr) {
    int i = blockIdx.x * 256 + threadIdx.x;
    if (i < NN) rowptr[i + 1] += bsum[i >> 10];
    if (i == 0) rowptr[0] = 0;
}

__global__ __launch_bounds__(256) void k_fill(const int* srcE, const int* dstE,
                                              const int* rowptr, int* fill, int* col, int* rowv) {
    int i = blockIdx.x * 256 + threadIdx.x;
    if (i >= NT) return;
    int s, d;
    if (i < NE) { s = srcE[i]; d = dstE[i]; }
    else        { s = i - NE; d = s; }        // self loop
    int p = rowptr[d] + atomicAdd(&fill[d], 1);
    col[p] = s;
    rowv[p] = d;
}

// ---------------- Layer 1 GEMM (f16 MFMA, DMA-staged): 64 rows/block, 4 waves x 16 rows ----------------
// Per-wave-private LDS (no barriers). x tile staged via global_load_lds (async DMA), 3 buffers deep,
// counted vmcnt waits. LDS dest linear (HW requirement); bank swizzle via pre-swizzled global source:
// physical 4-float block p = logical b ^ (row&7)  -> ds_read_b128 is bank-uniform (8 words/bank).

__global__ __launch_bounds__(256) void k_gemm1(const float* x, const unsigned* W1pT,
                                               const float* att_s, const float* att_d,
                                               const float* zsrc,
                                               __hip_bfloat16* h1b, float* aad1) {
    __shared__ float As[4][3 * 512];           // per wave: 3 rotating [16][32] f32 buffers (6 KiB)
    int tid = threadIdx.x;
    int l = tid & 63, w = tid >> 6;
    int n0 = blockIdx.x * 64 + w * 16;         // this wave's 16 rows
    float* bufs = As[w];
    int frow = l & 15;                         // A row / C col lane index
    int kg = l >> 4;                           // k-group 0..3 (8 k each)
    int rl = l >> 5;                           // DMA: row parity within issue
    int j2 = l & 3;                            // DMA: word within 4-float block
    int pb = (l >> 2) & 7;                     // DMA: physical block index
    f32x4_t acc[4] = {};

#define G1_DMA(S, BI)                                                              \
    {                                                                              \
        float* dst_ = bufs + (BI) * 512;                                           \
        _Pragma("unroll")                                                          \
        for (int i_ = 0; i_ < 8; i_++) {                                           \
            int r_ = i_ * 2 + rl;                                                  \
            int kk_ = ((pb ^ (r_ & 7)) << 2) | j2;                                 \
            int k_ = (S) * 32 + kk_;                                               \
            int n_ = n0 + r_;                                                      \
            const float* g_ = (n_ < NN && k_ < DIN) ? (x + (size_t)n_ * DIN + k_)  \
                                                    : (zsrc + l);                  \
            __builtin_amdgcn_global_load_lds((const AS1 float*)g_,                 \
                                             (AS3 float*)(dst_ + i_ * 64), 4, 0, 0); \
        }                                                                          \
    }

#define G1_LB(DST, S)                                                              \
    _Pragma("unroll")                                                              \
    for (int t_ = 0; t_ < 4; t_++)                                                 \
        DST[t_] = *(const uint4*)&W1pT[(t_ * 16 + frow) * 96 + (S) * 16 + kg * 4];

#define G1_STEP(S, VM)                                                             \
    {                                                                              \
        __builtin_amdgcn_sched_barrier(0);                                         \
        if ((S) < 5) { G1_LB(Bn, (S) + 1) }                                        \
        __builtin_amdgcn_sched_barrier(0);                                         \
        if ((S) < 4) { G1_DMA((S) + 2, ((S) + 2) % 3) }                            \
        __builtin_amdgcn_sched_barrier(0);                                         \
        asm volatile("s_waitcnt vmcnt(" #VM ")" ::: "memory");                     \
        __builtin_amdgcn_sched_barrier(0);                                         \
        {                                                                          \
            float* cb_ = bufs + ((S) % 3) * 512;                                   \
            int b0_ = ((2 * kg) ^ (frow & 7)) * 4;                                 \
            int b1_ = ((2 * kg + 1) ^ (frow & 7)) * 4;                             \
            float4 f0 = *(const float4*)&cb_[frow * 32 + b0_];                     \
            float4 f1 = *(const float4*)&cb_[frow * 32 + b1_];                     \
            f16x8_t av;                                                            \
            av[0] = (_Float16)f0.x; av[1] = (_Float16)f0.y;                        \
            av[2] = (_Float16)f0.z; av[3] = (_Float16)f0.w;                        \
            av[4] = (_Float16)f1.x; av[5] = (_Float16)f1.y;                        \
            av[6] = (_Float16)f1.z; av[7] = (_Float16)f1.w;                        \
            _Pragma("unroll")                                                      \
            for (int t_ = 0; t_ < 4; t_++)                                         \
                acc[t_] = __builtin_amdgcn_mfma_f32_16x16x32_f16(                  \
                    av, *(f16x8_t*)&Bn0[t_], acc[t_], 0, 0, 0);                    \
            _Pragma("unroll")                                                      \
            for (int t_ = 0; t_ < 4; t_++) Bn0[t_] = Bn[t_];                       \
        }                                                                          \
    }

    uint4 Bn0[4], Bn[4];
    G1_DMA(0, 0)
    G1_DMA(1, 1)
    G1_LB(Bn0, 0)
    G1_STEP(0, 12)
    G1_STEP(1, 20)
    G1_STEP(2, 20)
    G1_STEP(3, 20)
    G1_STEP(4, 12)
    G1_STEP(5, 0)

    // epilogue: bf16 h1 rows + attention partials
    // C/D layout: col = l&15 (-> c = t*16+frow), row = kg*4 + q  [m89]
    unsigned short* h1u = (unsigned short*)h1b;
    float asv[4], adv[4];
    #pragma unroll
    for (int t = 0; t < 4; t++) {
        int c = t * 16 + frow;
        asv[t] = att_s[c]; adv[t] = att_d[c];
    }
    int hb = (l >> 3) & 1;                     // which head within the tile's pair
    #pragma unroll
    for (int q = 0; q < 4; q++) {
        int n = n0 + kg * 4 + q;
        bool ok = (n < NN);
        #pragma unroll
        for (int t = 0; t < 4; t++) {
            if (ok) h1u[(size_t)n * 64 + t * 16 + frow] = f2bf(acc[t][q]);
            float sv = acc[t][q] * asv[t];
            float dv = acc[t][q] * adv[t];
            sv += __shfl_xor(sv, 1); sv += __shfl_xor(sv, 2); sv += __shfl_xor(sv, 4);
            dv += __shfl_xor(dv, 1); dv += __shfl_xor(dv, 2); dv += __shfl_xor(dv, 4);
            if (ok && (l & 7) == 0) {
                int h = t * 2 + hb;            // 8-col head within 64 cols
                aad1[(size_t)n * 16 + h]     = sv;
                aad1[(size_t)n * 16 + 8 + h] = dv;
            }
        }
    }
}

// ---------------- per-edge softmax numerators (bf16): we[e][h] = exp(leaky(as[s][h]+ad[d][h])) ----------------

__global__ __launch_bounds__(256) void k_edgew(const float* aad, const int* col, const int* rowv,
                                               __hip_bfloat16* web) {
    int e = blockIdx.x * 256 + threadIdx.x;
    if (e >= NT) return;
    int s = col[e], d = rowv[e];
    float4 s0 = *(const float4*)&aad[(size_t)s * 16];
    float4 s1 = *(const float4*)&aad[(size_t)s * 16 + 4];
    float4 dd0 = *(const float4*)&aad[(size_t)d * 16 + 8];
    float4 dd1 = *(const float4*)&aad[(size_t)d * 16 + 12];
    float as[8] = {s0.x, s0.y, s0.z, s0.w, s1.x, s1.y, s1.z, s1.w};
    float ad[8] = {dd0.x, dd0.y, dd0.z, dd0.w, dd1.x, dd1.y, dd1.z, dd1.w};
    unsigned p[4];
    #pragma unroll
    for (int q = 0; q < 4; q++) {
        float a0 = as[2*q]   + ad[2*q];
        float a1 = as[2*q+1] + ad[2*q+1];
        a0 = a0 > 0.f ? a0 : 0.2f * a0;
        a1 = a1 > 0.f ? a1 : 0.2f * a1;
        p[q] = (unsigned)f2bf(__expf(a0)) | ((unsigned)f2bf(__expf(a1)) << 16);
    }
    *(uint4*)&web[(size_t)e * 8] = make_uint4(p[0], p[1], p[2], p[3]);
}

// ---------------- Layer-1 aggregation: 16 lanes/node (4 ch each), 4-edge batches ----------------

__global__ __launch_bounds__(256) void k_agg1(const __hip_bfloat16* h1b, const __hip_bfloat16* we1b,
                                              const int* rowptr, const int* col,
                                              const float* b1, __hip_bfloat16* out1b) {
    int tid = threadIdx.x;
    int q = tid & 15;                          // channel quad within node
    int n = blockIdx.x * 16 + (tid >> 4);     // NN = 16*6250 exact
    int hq = q >> 1;                           // head of channels 4q..4q+3
    const unsigned short* h1u = (const unsigned short*)h1b;
    const unsigned short* weu = (const unsigned short*)we1b;
    int rs = rowptr[n], re = rowptr[n + 1];
    float acc0 = 0.f, acc1 = 0.f, acc2 = 0.f, acc3 = 0.f, den = 0.f;
    for (int eb = rs; eb < re; eb += 4) {
        int c4[4];
        #pragma unroll
        for (int j = 0; j < 4; j++) c4[j] = col[min(eb + j, re - 1)];   // batched col loads
        #pragma unroll
        for (int j = 0; j < 4; j++) {
            int e = min(eb + j, re - 1);
            float wv = bfu(weu[(size_t)e * 8 + hq]);
            wv = (eb + j < re) ? wv : 0.f;                              // predicate after load
            uint2 hv = *(const uint2*)&h1u[(size_t)c4[j] * 64 + q * 4]; // batched row gathers
            den  += wv;
            acc0 += wv * bfu((unsigned short)(hv.x & 0xffff));
            acc1 += wv * bfu((unsigned short)(hv.x >> 16));
            acc2 += wv * bfu((unsigned short)(hv.y & 0xffff));
            acc3 += wv * bfu((unsigned short)(hv.y >> 16));
        }
    }
    float4 bb = *(const float4*)&b1[q * 4];
    float dd = den + 1e-16f;
    unsigned short* ou = (unsigned short*)out1b;
    unsigned p0 = (unsigned)f2bf(acc0 / dd + bb.x) | ((unsigned)f2bf(acc1 / dd + bb.y) << 16);
    unsigned p1 = (unsigned)f2bf(acc2 / dd + bb.z) | ((unsigned)f2bf(acc3 / dd + bb.w) << 16);
    *(uint2*)&ou[(size_t)n * 64 + q * 4] = make_uint2(p0, p1);
}

// ---------------- layer-2 logits: aad2[n][j] = <out1[n], wsd[j]>, LDS-staged GEMV ----------------

__global__ __launch_bounds__(256) void k_att2(const __hip_bfloat16* out1b, const float* wsd,
                                              float* aad2) {
    __shared__ float t[64][65];
    int tid = threadIdx.x;
    int n0 = blockIdx.x * 64;
    const unsigned short* o1u = (const unsigned short*)out1b;
    #pragma unroll
    for (int l = 0; l < 4; l++) {
        int q = tid + l * 256;               // 1024 chunks of 4 bf16 in the 64x64 tile
        int r = q >> 4, c4 = q & 15;
        int n = n0 + r;
        uint2 v = make_uint2(0, 0);
        if (n < NN) v = *(const uint2*)&o1u[(size_t)n * 64 + c4 * 4];
        t[r][c4 * 4 + 0] = bfu((unsigned short)(v.x & 0xffff));
        t[r][c4 * 4 + 1] = bfu((unsigned short)(v.x >> 16));
        t[r][c4 * 4 + 2] = bfu((unsigned short)(v.y & 0xffff));
        t[r][c4 * 4 + 3] = bfu((unsigned short)(v.y >> 16));
    }
    __syncthreads();
    int lane = tid & 63;
    int j0 = __builtin_amdgcn_readfirstlane((tid >> 6) * 4);   // wave-uniform -> scalar wsd loads
    int n = n0 + lane;
    float a0 = 0.f, a1 = 0.f, a2 = 0.f, a3 = 0.f;
    #pragma unroll 8
    for (int k = 0; k < 64; k++) {
        float ov = t[lane][k];               // (lane+k)%32 banks: 2-way, free
        a0 += ov * wsd[(j0 + 0) * 64 + k];
        a1 += ov * wsd[(j0 + 1) * 64 + k];
        a2 += ov * wsd[(j0 + 2) * 64 + k];
        a3 += ov * wsd[(j0 + 3) * 64 + k];
    }
    if (n < NN) *(float4*)&aad2[(size_t)n * 16 + j0] = make_float4(a0, a1, a2, a3);
}

// ---------------- Layer-2 aggregation: 32 lanes/node (2 ch x 8 heads), 4-edge batches ----------------

__global__ __launch_bounds__(256) void k_agg2(const __hip_bfloat16* out1b, const __hip_bfloat16* we2b,
                                              const int* rowptr, const int* col,
                                              __hip_bfloat16* aggb, int n0, int n1) {
    int tid = threadIdx.x;
    int p = tid & 31;                          // channel pair within node
    int n = n0 + blockIdx.x * 8 + (tid >> 5);  // CHUNK = 8*6250 exact
    const unsigned short* o1u = (const unsigned short*)out1b;
    const unsigned short* weu = (const unsigned short*)we2b;
    int rs = rowptr[n], re = rowptr[n + 1];
    float den[8] = {}, a0[8] = {}, a1[8] = {};
    for (int eb = rs; eb < re; eb += 4) {
        int c4[4];
        #pragma unroll
        for (int j = 0; j < 4; j++) c4[j] = col[min(eb + j, re - 1)];   // batched col loads
        #pragma unroll
        for (int j = 0; j < 4; j++) {
            int e = min(eb + j, re - 1);
            uint4 wv = *(const uint4*)&weu[(size_t)e * 8];              // uniform per edge
            unsigned hv = *(const unsigned*)&o1u[(size_t)c4[j] * 64 + p * 2];
            float vmul = (eb + j < re) ? 1.f : 0.f;
            float h0 = bfu((unsigned short)(hv & 0xffff));
            float h1 = bfu((unsigned short)(hv >> 16));
            float wts[8] = {bfu((unsigned short)(wv.x & 0xffff)), bfu((unsigned short)(wv.x >> 16)),
                            bfu((unsigned short)(wv.y & 0xffff)), bfu((unsigned short)(wv.y >> 16)),
                            bfu((unsigned short)(wv.z & 0xffff)), bfu((unsigned short)(wv.z >> 16)),
                            bfu((unsigned short)(wv.w & 0xffff)), bfu((unsigned short)(wv.w >> 16))};
            #pragma unroll
            for (int hh = 0; hh < 8; hh++) {
                float ww = wts[hh] * vmul;
                den[hh] += ww;
                a0[hh] += ww * h0;
                a1[hh] += ww * h1;
            }
        }
    }
    size_t base = (size_t)(n - n0) * 512;
    unsigned short* au = (unsigned short*)aggb;
    #pragma unroll
    for (int hh = 0; hh < 8; hh++) {
        float dd = den[hh] + 1e-16f;
        unsigned pp = (unsigned)f2bf(a0[hh] / dd) | ((unsigned)f2bf(a1[hh] / dd) << 16);
        *(unsigned*)&au[base + hh * 64 + p * 2] = pp;
    }
}

// ---------------- gemm2 (bf16 MFMA): out2Tb[c][n] = bf16(0.125 * aggb[n] @ W2pT[c]^T + b2[c]) ----------------

__global__ __launch_bounds__(256) void k_gemm2(const __hip_bfloat16* aggb, const __hip_bfloat16* W2pT,
                                               const float* b2, __hip_bfloat16* out2Tb, int n0, int n1) {
    __shared__ float smem[4608];               // 18432 B: A_lds 64x72 bf16 | B_lds 64x72 bf16; reused as [64][66] f32
    unsigned short* A_lds = (unsigned short*)smem;           // [64][72] bf16, row 144 B
    unsigned short* B_lds = A_lds + 64 * 72;                 // [64][72] bf16
    const unsigned short* A_g = (const unsigned short*)aggb;
    const unsigned short* B_g = (const unsigned short*)W2pT;
    int tid = threadIdx.x;
    int w = tid >> 6, l = tid & 63;
    int m0 = blockIdx.x * 64;
    int rows = n1 - n0;
    f32x4_t acc[4] = {};                       // 4 col-tiles for this wave's 16-row band
    for (int k0 = 0; k0 < 512; k0 += 64) {
        #pragma unroll
        for (int ll = 0; ll < 2; ll++) {
            int u = tid + ll * 256;            // [0,512): r = row/col (64), seg = 8x8 bf16
            int r = u >> 3, seg = u & 7;
            uint4 va = make_uint4(0, 0, 0, 0);
            if (m0 + r < rows) va = *(const uint4*)&A_g[(size_t)(m0 + r) * 512 + k0 + seg * 8];
            *(uint4*)&A_lds[r * 72 + seg * 8] = va;
            *(uint4*)&B_lds[r * 72 + seg * 8] = *(const uint4*)&B_g[(size_t)r * 512 + k0 + seg * 8];
        }
        __syncthreads();
        #pragma unroll
        for (int kk = 0; kk < 2; kk++) {
            bf16x8_t a = *(const bf16x8_t*)&A_lds[(w * 16 + (l & 15)) * 72 + kk * 32 + (l >> 4) * 8];
            #pragma unroll
            for (int t = 0; t < 4; t++) {
                bf16x8_t bb = *(const bf16x8_t*)&B_lds[(t * 16 + (l & 15)) * 72 + kk * 32 + (l >> 4) * 8];
                acc[t] = __builtin_amdgcn_mfma_f32_16x16x32_bf16(a, bb, acc[t], 0, 0, 0);
            }
        }
        __syncthreads();
    }
    // epilogue: scale+bias into LDS f32 bounce, then coalesced transposed bf16 store
    #pragma unroll
    for (int t = 0; t < 4; t++) {
        int col_l = l & 15;
        float bias = b2[t * 16 + col_l];
        #pragma unroll
        for (int q = 0; q < 4; q++) {
            int row_l = (l >> 4) * 4 + q;      // C/D: col=lane&15, row=(lane>>4)*4+reg [m89]
            smem[(w * 16 + row_l) * 66 + t * 16 + col_l] = 0.125f * acc[t][q] + bias;
        }
    }
    __syncthreads();
    unsigned short* o2u = (unsigned short*)out2Tb;
    int ml = tid & 63, cr = tid >> 6;
    #pragma unroll
    for (int p = 0; p < 16; p++) {
        int c = p * 4 + cr;
        int gr = m0 + ml;
        if (gr < rows) o2u[(size_t)c * NN + (n0 + gr)] = f2bf(smem[ml * 66 + c]);
    }
}

// ---------------- MLP heads + CE: packed-h2 o tile in LDS, dot2 inner, 16+16 accumulators ----------------

__global__ __launch_bounds__(256) void k_mlp(const __hip_bfloat16* out2Tb,
                                             const unsigned* tswp, const float* tsb1,
                                             const float* tsw2, const float* tsb2,
                                             const unsigned* cwp, const float* cb1,
                                             const float* cw2, const float* cb2,
                                             const int* tst, const int* ctg, const unsigned char* msk,
                                             float* part) {
    __shared__ unsigned t2h[32 * 64];          // [kp][node_local] packed half2 (o[2kp], o[2kp+1])
    __shared__ float red[4][7][64];
    int tid = threadIdx.x;
    int lane = tid & 63;
    int w = tid >> 6;
    int n0 = blockIdx.x * 64;
    int nstage = n0 + lane; if (nstage >= NN) nstage = NN - 1;
    const unsigned short* o2u = (const unsigned short*)out2Tb;
    #pragma unroll
    for (int l = 0; l < 8; l++) {
        int kp = w * 8 + l;
        float e0 = bfu(o2u[(size_t)(2 * kp) * NN + nstage]);       // coalesced
        float e1 = bfu(o2u[(size_t)(2 * kp + 1) * NN + nstage]);
        t2h[kp * 64 + lane] = pkh2(e0, e1);
    }
    __syncthreads();

    int c0 = __builtin_amdgcn_readfirstlane(w * 16);          // wave-uniform -> scalar weight loads
    int n = n0 + lane;
    float vts[16], vcls[16];
    #pragma unroll
    for (int j = 0; j < 16; j++) { vts[j] = tsb1[c0 + j]; vcls[j] = cb1[c0 + j]; }
    for (int kp = 0; kp < 32; kp++) {
        unsigned ou = t2h[kp * 64 + lane];                    // conflict-free (stride 64, 1 row)
        h2_t ov = *(h2_t*)&ou;
        const unsigned* wt = &tswp[kp * 64 + c0];             // wave-uniform -> s_load_dwordx4
        const unsigned* wc = &cwp[kp * 64 + c0];
        #pragma unroll
        for (int j = 0; j < 16; j++) {
            unsigned wtv = wt[j], wcv = wc[j];
            vts[j]  = __builtin_amdgcn_fdot2(ov, *(h2_t*)&wtv, vts[j], false);
            vcls[j] = __builtin_amdgcn_fdot2(ov, *(h2_t*)&wcv, vcls[j], false);
        }
    }
    float lg[5] = {0.f, 0.f, 0.f, 0.f, 0.f};
    float lg2[2] = {0.f, 0.f};
    #pragma unroll
    for (int j = 0; j < 16; j++) {
        int c = c0 + j;
        float v = fmaxf(vts[j], 0.f);
        #pragma unroll
        for (int t = 0; t < 5; t++) lg[t] += v * tsw2[c * 5 + t];
        float v2 = fmaxf(vcls[j], 0.f);
        lg2[0] += v2 * cw2[c * 2];
        lg2[1] += v2 * cw2[c * 2 + 1];
    }
    #pragma unroll
    for (int t = 0; t < 5; t++) red[w][t][lane] = lg[t];
    red[w][5][lane] = lg2[0];
    red[w][6][lane] = lg2[1];
    __syncthreads();
    if (w == 0) {
        float tsl = 0.f, cll = 0.f, mval = 0.f;
        if (n < NN) {
            float L[5];
            #pragma unroll
            for (int t = 0; t < 5; t++)
                L[t] = red[0][t][lane] + red[1][t][lane] + red[2][t][lane] + red[3][t][lane] + tsb2[t];
            float mx = L[0];
            #pragma unroll
            for (int t = 1; t < 5; t++) mx = fmaxf(mx, L[t]);
            float se = 0.f;
            #pragma unroll
            for (int t = 0; t < 5; t++) se += __expf(L[t] - mx);
            int tg = tst[n];
            float pick = 0.f;
            #pragma unroll
            for (int t = 0; t < 5; t++) pick += (t == tg) ? L[t] : 0.f;
            tsl = mx + __logf(se) - pick;
            float C0 = red[0][5][lane] + red[1][5][lane] + red[2][5][lane] + red[3][5][lane] + cb2[0];
            float C1 = red[0][6][lane] + red[1][6][lane] + red[2][6][lane] + red[3][6][lane] + cb2[1];
            float mx2 = fmaxf(C0, C1);
            float lse2 = mx2 + __logf(__expf(C0 - mx2) + __expf(C1 - mx2));
            mval = msk[n] ? 1.f : 0.f;
            float pick2 = ctg[n] ? C1 : C0;
            cll = (lse2 - pick2) * mval;
        }
        #pragma unroll
        for (int off = 1; off < 64; off <<= 1) {
            tsl  += __shfl_xor(tsl, off);
            cll  += __shfl_xor(cll, off);
            mval += __shfl_xor(mval, off);
        }
        if (lane == 0) {
            part[blockIdx.x * 3 + 0] = tsl;
            part[blockIdx.x * 3 + 1] = cll;
            part[blockIdx.x * 3 + 2] = mval;
        }
    }
}

__global__ __launch_bounds__(256) void k_final(const float* part, float* out, int nb) {
    __shared__ float sm[3][256];
    int tid = threadIdx.x;
    float a = 0, b = 0, c = 0;
    for (int i = tid; i < nb; i += 256) { a += part[i*3]; b += part[i*3+1]; c += part[i*3+2]; }
    sm[0][tid] = a; sm[1][tid] = b; sm[2][tid] = c;
    __syncthreads();
    for (int s = 128; s > 0; s >>= 1) {
        if (tid < s) {
            sm[0][tid] += sm[0][tid + s];
            sm[1][tid] += sm[1][tid + s];
            sm[2][tid] += sm[2][tid + s];
        }
        __syncthreads();
    }
    if (tid == 0) out[0] = sm[1][0] / sm[2][0] + sm[0][0] / (float)NN;
}

// ---------------- host ----------------

extern "C" void kernel_launch(void* const* d_in, const int* in_sizes, int n_in,
                              void* d_out, int out_size, void* d_ws, size_t ws_size,
                              hipStream_t stream) {
    const float* x    = (const float*)d_in[0];
    const int*   ei   = (const int*)d_in[1];
    const int*   tst  = (const int*)d_in[2];
    const int*   ctg  = (const int*)d_in[3];
    const unsigned char* msk = (const unsigned char*)d_in[4];
    const float* W1   = (const float*)d_in[5];
    const float* a1s  = (const float*)d_in[6];
    const float* a1d  = (const float*)d_in[7];
    const float* b1   = (const float*)d_in[8];
    const float* W2   = (const float*)d_in[9];
    const float* a2s  = (const float*)d_in[10];
    const float* a2d  = (const float*)d_in[11];
    const float* b2   = (const float*)d_in[12];
    const float* tsw1 = (const float*)d_in[13];
    const float* tsb1 = (const float*)d_in[14];
    const float* tsw2 = (const float*)d_in[15];
    const float* tsb2 = (const float*)d_in[16];
    const float* cw1  = (const float*)d_in[17];
    const float* cb1  = (const float*)d_in[18];
    const float* cw2  = (const float*)d_in[19];
    const float* cb2  = (const float*)d_in[20];
    const int* srcE = ei;
    const int* dstE = ei + NE;

    char* ws = (char*)d_ws;
    size_t off = 0;
    auto alloc = [&](size_t b) { size_t o = off; off = (off + b + 255) & ~(size_t)255; return o; };
    int*   cnt    = (int*)(ws + alloc((size_t)NN * 4));
    int*   fill   = (int*)(ws + alloc((size_t)NN * 4));
    int*   rowptr = (int*)(ws + alloc((size_t)(NN + 1) * 4));
    int*   bsum   = (int*)(ws + alloc(128 * 4));
    int*   col    = (int*)(ws + alloc((size_t)NT * 4));
    int*   rowv   = (int*)(ws + alloc((size_t)NT * 4));
    float* aad1   = (float*)(ws + alloc((size_t)NN * 16 * 4));
    __hip_bfloat16* out1b = (__hip_bfloat16*)(ws + alloc((size_t)NN * 64 * 2));
    float* aad2   = (float*)(ws + alloc((size_t)NN * 16 * 4));
    float* wsd    = (float*)(ws + alloc(1024 * 4));
    __hip_bfloat16* W2pT  = (__hip_bfloat16*)(ws + alloc(32768 * 2));
    unsigned* tswp = (unsigned*)(ws + alloc(2048 * 4));
    unsigned* cwp  = (unsigned*)(ws + alloc(2048 * 4));
    unsigned* W1pT = (unsigned*)(ws + alloc(6144 * 4));
    float* zbuf   = (float*)(ws + alloc(64 * 4));
    __hip_bfloat16* out2Tb = (__hip_bfloat16*)(ws + alloc((size_t)NN * 64 * 2));
    __hip_bfloat16* h1b   = (__hip_bfloat16*)(ws + alloc((size_t)NN * 64 * 2));
    __hip_bfloat16* aggb  = (__hip_bfloat16*)(ws + alloc((size_t)CHUNK * 512 * 2));
    __hip_bfloat16* web   = (__hip_bfloat16*)(ws + alloc((size_t)NT * 8 * 2));
    float* part   = (float*)(ws + alloc((size_t)NODEB * 3 * 4));
    (void)ws_size; (void)in_sizes; (void)n_in; (void)out_size;

    int nb_scan = (NN + 1023) / 1024;  // 98

    k_misc<<<MISCGRID, 256, 0, stream>>>(W2, a2s, a2d, wsd, W2pT, cnt, fill,
                                         tsw1, cw1, tswp, cwp, W1, W1pT, zbuf);
    k_count<<<(NE + 255) / 256, 256, 0, stream>>>(dstE, cnt);
    k_scanA<<<nb_scan, 256, 0, stream>>>(cnt, rowptr, bsum);
    k_scanB<<<1, 64, 0, stream>>>(bsum, nb_scan);
    k_scanC<<<(NN + 255) / 256, 256, 0, stream>>>(bsum, rowptr);
    k_fill<<<(NT + 255) / 256, 256, 0, stream>>>(srcE, dstE, rowptr, fill, col, rowv);

    k_gemm1<<<NODEB, 256, 0, stream>>>(x, W1pT, a1s, a1d, zbuf, h1b, aad1);
    k_edgew<<<(NT + 255) / 256, 256, 0, stream>>>(aad1, col, rowv, web);
    k_agg1<<<NN / 16, 256, 0, stream>>>(h1b, web, rowptr, col, b1, out1b);
    k_att2<<<NODEB, 256, 0, stream>>>(out1b, wsd, aad2);
    k_edgew<<<(NT + 255) / 256, 256, 0, stream>>>(aad2, col, rowv, web);

    for (int c = 0; c < 2; c++) {
        int n0 = c * CHUNK, n1 = n0 + CHUNK;
        k_agg2<<<CHUNK / 8, 256, 0, stream>>>(out1b, web, rowptr, col, aggb, n0, n1);
        k_gemm2<<<(CHUNK + 63) / 64, 256, 0, stream>>>(aggb, W2pT, b2, out2Tb, n0, n1);
    }

    k_mlp<<<NODEB, 256, 0, stream>>>(out2Tb, tswp, tsb1, tsw2, tsb2,
                                     cwp, cb1, cw2, cb2, tst, ctg, msk, part);
    k_final<<<1, 256, 0, stream>>>(part, (float*)d_out, NODEB);
}

// Round 3
// 213.525 us; speedup vs baseline: 1.1499x; 1.0030x over previous
//
#include <hip/hip_runtime.h>
#include <hip/hip_bf16.h>

#define NN 100000      // nodes
#define NE 200000      // edges (without self loops)
#define NT (NE + NN)   // total edges incl self loops
#define DIN 165
#define CHUNK 50000    // node chunk for agg/gemm2 (2 chunks)
#define PREPB 128
#define INITB 391
#define PACKB 8        // 2048 threads: kp in [0,32), c in [0,64)
#define W1PB 24        // W1 f16 [c][192] pack: 6144 u32
#define MISCGRID (PREPB + INITB + PACKB + W1PB)
#define NODEB 1563     // ceil(NN/64) blocks (64-node tiles)
#define XDW ((size_t)NN * DIN)   // total x dwords (16.5M, divisible by 4)
#define NDMA 42                  // 42 KiB staged per 64-row tile (need 42364B, have 43008B)

typedef __attribute__((ext_vector_type(8))) short bf16x8_t;
typedef __attribute__((ext_vector_type(4))) float f32x4_t;
typedef _Float16 h2_t __attribute__((ext_vector_type(2)));
typedef _Float16 f16x8_t __attribute__((ext_vector_type(8)));

#define AS1 __attribute__((address_space(1)))
#define AS3 __attribute__((address_space(3)))

static __device__ __forceinline__ unsigned short f2bf(float f) {
    __hip_bfloat16 b = __float2bfloat16(f);
    return *(unsigned short*)&b;
}
static __device__ __forceinline__ float bfu(unsigned short u) {
    __hip_bfloat16 b = *(__hip_bfloat16*)&u;
    return __bfloat162float(b);
}
static __device__ __forceinline__ unsigned pkh2(float a, float b) {
    h2_t v; v[0] = (_Float16)a; v[1] = (_Float16)b;
    return *(unsigned*)&v;
}

// ---------------- merged: layer-2 prep (bf16 W2pT + wsd) | CSR init | mlp weight pack | W1 f16 pack ----------------

__global__ __launch_bounds__(256) void k_misc(const float* W2, const float* a2s, const float* a2d,
                                              float* wsd, __hip_bfloat16* W2pT,
                                              int* cnt, int* fill,
                                              const float* tsw1, const float* cw1,
                                              unsigned* tswp, unsigned* cwp,
                                              const float* W1, unsigned* W1pT, float* zbuf) {
    int b = blockIdx.x;
    int tid = threadIdx.x;
    if (b < PREPB) {
        int i = b * 256 + tid;                 // [0, 32768)
        // W2pT[c][j] = bf16(W2[kk*512 + h*64 + c]),  j = h*64 + kk
        int c = i >> 9, j = i & 511;
        int hh = j >> 6, kk = j & 63;
        W2pT[i] = __float2bfloat16(W2[kk * 512 + hh * 64 + c]);
        if (b == 0) zbuf[tid] = 0.f;           // 256-float zero source for gemm1 DMA padding
        if (i < 512) {
            int h = i >> 6, k = i & 63;
            float s = 0.f, d = 0.f;
            for (int cc = 0; cc < 64; cc++) {
                float w = W2[k * 512 + h * 64 + cc];
                s += w * a2s[h * 64 + cc];
                d += w * a2d[h * 64 + cc];
            }
            wsd[i] = s; wsd[512 + i] = d;
        }
    } else if (b < PREPB + INITB) {
        int i = (b - PREPB) * 256 + tid;
        if (i < NN) { cnt[i] = 0; fill[i] = 0; }
    } else if (b < PREPB + INITB + PACKB) {
        int i = (b - PREPB - INITB) * 256 + tid;  // [0, 2048): kp*64+c
        if (i < 2048) {
            int kp = i >> 6, c = i & 63;           // kp in [0,32)
            tswp[i] = pkh2(tsw1[(2 * kp) * 64 + c], tsw1[(2 * kp + 1) * 64 + c]);
            cwp[i]  = pkh2(cw1[(2 * kp) * 64 + c],  cw1[(2 * kp + 1) * 64 + c]);
        }
    } else {
        int i = (b - PREPB - INITB - PACKB) * 256 + tid;  // [0, 6144): c*96 + kp
        if (i < 6144) {
            int c = i / 96, kp = i - c * 96;
            int k = 2 * kp;
            float f0 = (k < DIN) ? W1[k * 64 + c] : 0.f;
            float f1 = (k + 1 < DIN) ? W1[(k + 1) * 64 + c] : 0.f;
            W1pT[i] = pkh2(f0, f1);               // [c][96] u32 = [c][192] f16, zero-padded K
        }
    }
}

// ---------------- CSR build ----------------

__global__ __launch_bounds__(256) void k_count(const int* dstE, int* cnt) {
    int e = blockIdx.x * 256 + threadIdx.x;
    if (e < NE) atomicAdd(&cnt[dstE[e]], 1);
}

// per-block inclusive scan of 1024 elements (256 thr x 4); +1 accounts the self loop
__global__ __launch_bounds__(256) void k_scanA(const int* cnt, int* rowptr, int* bsum) {
    __shared__ int sm[256];
    int t = threadIdx.x;
    int base = blockIdx.x * 1024;
    int v[4]; int s = 0;
    for (int i = 0; i < 4; i++) {
        int idx = base + t * 4 + i;
        v[i] = (idx < NN) ? (cnt[idx] + 1) : 0;
        s += v[i];
    }
    sm[t] = s; __syncthreads();
    for (int off = 1; off < 256; off <<= 1) {
        int x = (t >= off) ? sm[t - off] : 0;
        __syncthreads();
        sm[t] += x;
        __syncthreads();
    }
    int run = sm[t] - s;
    for (int i = 0; i < 4; i++) {
        run += v[i];
        int idx = base + t * 4 + i;
        if (idx < NN) rowptr[idx + 1] = run;
    }
    if (t == 255) bsum[blockIdx.x] = sm[255];
}

// exclusive scan of nb (<=128) block sums, one wave
__global__ __launch_bounds__(64) void k_scanB(int* bsum, int nb) {
    int lane = threadIdx.x;
    int v0 = (lane < nb) ? bsum[lane] : 0;
    int v1 = (64 + lane < nb) ? bsum[64 + lane] : 0;
    int s0 = v0;
    for (int off = 1; off < 64; off <<= 1) { int t = __shfl_up(s0, off); if (lane >= off) s0 += t; }
    int tot0 = __shfl(s0, 63);
    int s1 = v1;
    for (int off = 1; off < 64; off <<= 1) { int t = __shfl_up(s1, off); if (lane >= off) s1 += t; }
    if (lane < nb) bsum[lane] = s0 - v0;
    if (64 + lane < nb) bsum[64 + lane] = tot0 + s1 - v1;
}

__global__ __launch_bounds__(256) void k_scanC(const int* bsum, int* rowptr) {
    int i = blockIdx.x * 256 + threadIdx.x;
    if (i < NN) rowptr[i + 1] += bsum[i >> 10];
    if (i == 0) rowptr[0] = 0;
}

__global__ __launch_bounds__(256) void k_fill(const int* srcE, const int* dstE,
                                              const int* rowptr, int* fill, int* col, int* rowv) {
    int i = blockIdx.x * 256 + threadIdx.x;
    if (i >= NT) return;
    int s, d;
    if (i < NE) { s = srcE[i]; d = dstE[i]; }
    else        { s = i - NE; d = s; }        // self loop
    int p = rowptr[d] + atomicAdd(&fill[d], 1);
    col[p] = s;
    rowv[p] = d;
}

// ---------------- Layer 1 GEMM (f16 MFMA): whole-tile burst staging ----------------
// The 64x165 f32 tile is CONTIGUOUS in x (n0*660B, always 16B-aligned since n0%4==0).
// Stage it in ONE burst: 42 x 1KB global_load_lds dwordx4 (wave-split) + all 24 B-frag
// loads (24KB W1pT, L2-resident) in flight together -> one latency round per block,
// ~66KB in flight per block, 3 blocks/CU. Then 6 pure-LDS MFMA steps.
// LDS reads at row stride 165: bank (5*frow + 8*kg + j) mod 32 = balanced 2-way (free).
// Over-read past k=165 into the next row is annihilated by W1pT's zero-padded K.

__global__ __launch_bounds__(256) void k_gemm1(const float* x, const unsigned* W1pT,
                                               const float* att_s, const float* att_d,
                                               const float* zsrc,
                                               __hip_bfloat16* h1b, float* aad1) {
    __shared__ float X[NDMA * 256];            // 43008 B staged tile; reused as h1 bounce
    int tid = threadIdx.x;
    int l = tid & 63, w = tid >> 6;
    int n0 = blockIdx.x * 64;
    int frow = l & 15, kg = l >> 4;

    // ---- burst-stage the whole tile (lane-ordered linear DMA) ----
    size_t tb = (size_t)n0 * DIN;              // tile start dword (16B-aligned)
    for (int i = w; i < NDMA; i += 4) {
        size_t gd = tb + (size_t)i * 256 + (size_t)l * 4;
        const float* g = (gd + 4 <= XDW) ? (x + gd) : (zsrc + l * 4);  // no straddle: XDW%4==0
        __builtin_amdgcn_global_load_lds((const AS1 float*)g,
                                         (AS3 float*)(X + i * 256), 16, 0, 0);
    }
    // ---- preload ALL B fragments (whole W1pT per wave) while DMA flies ----
    uint4 B[6][4];
    #pragma unroll
    for (int s = 0; s < 6; s++)
        #pragma unroll
        for (int t = 0; t < 4; t++)
            B[s][t] = *(const uint4*)&W1pT[(t * 16 + frow) * 96 + s * 16 + kg * 4];
    __syncthreads();                           // drains vmcnt: tile + B ready

    // ---- 6 MFMA steps, all operands local ----
    f32x4_t acc[4] = {};
    int rbase = (w * 16 + frow) * DIN + kg * 8;
    #pragma unroll
    for (int s = 0; s < 6; s++) {
        float f[8];
        #pragma unroll
        for (int j = 0; j < 8; j++) f[j] = X[rbase + s * 32 + j];
        f16x8_t av;
        #pragma unroll
        for (int j = 0; j < 8; j++) av[j] = (_Float16)f[j];
        #pragma unroll
        for (int t = 0; t < 4; t++)
            acc[t] = __builtin_amdgcn_mfma_f32_16x16x32_f16(av, *(f16x8_t*)&B[s][t], acc[t], 0, 0, 0);
    }

    // ---- attention partials from f32 acc (8-lane head-group shfl reduce) ----
    // C/D layout: col = l&15 (-> c = t*16+frow), row = kg*4 + q  [m89]
    int nw = n0 + w * 16;
    float asv[4], adv[4];
    #pragma unroll
    for (int t = 0; t < 4; t++) {
        int c = t * 16 + frow;
        asv[t] = att_s[c]; adv[t] = att_d[c];
    }
    int hb = (l >> 3) & 1;
    #pragma unroll
    for (int q = 0; q < 4; q++) {
        int n = nw + kg * 4 + q;
        bool ok = (n < NN);
        #pragma unroll
        for (int t = 0; t < 4; t++) {
            float sv = acc[t][q] * asv[t];
            float dv = acc[t][q] * adv[t];
            sv += __shfl_xor(sv, 1); sv += __shfl_xor(sv, 2); sv += __shfl_xor(sv, 4);
            dv += __shfl_xor(dv, 1); dv += __shfl_xor(dv, 2); dv += __shfl_xor(dv, 4);
            if (ok && (l & 7) == 0) {
                int h = t * 2 + hb;
                aad1[(size_t)n * 16 + h]     = sv;
                aad1[(size_t)n * 16 + 8 + h] = dv;
            }
        }
    }

    // ---- h1 via LDS bounce -> coalesced 32B/lane stores ----
    __syncthreads();                           // everyone done reading x from X
    unsigned short* Hw = (unsigned short*)X + w * 1152;    // per-wave [16][72] bf16
    #pragma unroll
    for (int t = 0; t < 4; t++)
        #pragma unroll
        for (int q = 0; q < 4; q++)
            Hw[(kg * 4 + q) * 72 + t * 16 + frow] = f2bf(acc[t][q]);
    int rr = l >> 2, cc = l & 3;
    int n2 = nw + rr;
    if (n2 < NN) {
        unsigned short* dst = (unsigned short*)h1b + (size_t)n2 * 64 + cc * 16;
        *(uint4*)dst       = *(const uint4*)&Hw[rr * 72 + cc * 16];
        *(uint4*)(dst + 8) = *(const uint4*)&Hw[rr * 72 + cc * 16 + 8];
    }
}

// ---------------- per-edge softmax numerators (bf16): we[e][h] = exp(leaky(as[s][h]+ad[d][h])) ----------------

__global__ __launch_bounds__(256) void k_edgew(const float* aad, const int* col, const int* rowv,
                                               __hip_bfloat16* web) {
    int e = blockIdx.x * 256 + threadIdx.x;
    if (e >= NT) return;
    int s = col[e], d = rowv[e];
    float4 s0 = *(const float4*)&aad[(size_t)s * 16];
    float4 s1 = *(const float4*)&aad[(size_t)s * 16 + 4];
    float4 dd0 = *(const float4*)&aad[(size_t)d * 16 + 8];
    float4 dd1 = *(const float4*)&aad[(size_t)d * 16 + 12];
    float as[8] = {s0.x, s0.y, s0.z, s0.w, s1.x, s1.y, s1.z, s1.w};
    float ad[8] = {dd0.x, dd0.y, dd0.z, dd0.w, dd1.x, dd1.y, dd1.z, dd1.w};
    unsigned p[4];
    #pragma unroll
    for (int q = 0; q < 4; q++) {
        float a0 = as[2*q]   + ad[2*q];
        float a1 = as[2*q+1] + ad[2*q+1];
        a0 = a0 > 0.f ? a0 : 0.2f * a0;
        a1 = a1 > 0.f ? a1 : 0.2f * a1;
        p[q] = (unsigned)f2bf(__expf(a0)) | ((unsigned)f2bf(__expf(a1)) << 16);
    }
    *(uint4*)&web[(size_t)e * 8] = make_uint4(p[0], p[1], p[2], p[3]);
}

// ---------------- Layer-1 aggregation: 16 lanes/node (4 ch each), 4-edge batches ----------------

__global__ __launch_bounds__(256) void k_agg1(const __hip_bfloat16* h1b, const __hip_bfloat16* we1b,
                                              const int* rowptr, const int* col,
                                              const float* b1, __hip_bfloat16* out1b) {
    int tid = threadIdx.x;
    int q = tid & 15;                          // channel quad within node
    int n = blockIdx.x * 16 + (tid >> 4);     // NN = 16*6250 exact
    int hq = q >> 1;                           // head of channels 4q..4q+3
    const unsigned short* h1u = (const unsigned short*)h1b;
    const unsigned short* weu = (const unsigned short*)we1b;
    int rs = rowptr[n], re = rowptr[n + 1];
    float acc0 = 0.f, acc1 = 0.f, acc2 = 0.f, acc3 = 0.f, den = 0.f;
    for (int eb = rs; eb < re; eb += 4) {
        int c4[4];
        #pragma unroll
        for (int j = 0; j < 4; j++) c4[j] = col[min(eb + j, re - 1)];   // batched col loads
        #pragma unroll
        for (int j = 0; j < 4; j++) {
            int e = min(eb + j, re - 1);
            float wv = bfu(weu[(size_t)e * 8 + hq]);
            wv = (eb + j < re) ? wv : 0.f;                              // predicate after load
            uint2 hv = *(const uint2*)&h1u[(size_t)c4[j] * 64 + q * 4]; // batched row gathers
            den  += wv;
            acc0 += wv * bfu((unsigned short)(hv.x & 0xffff));
            acc1 += wv * bfu((unsigned short)(hv.x >> 16));
            acc2 += wv * bfu((unsigned short)(hv.y & 0xffff));
            acc3 += wv * bfu((unsigned short)(hv.y >> 16));
        }
    }
    float4 bb = *(const float4*)&b1[q * 4];
    float dd = den + 1e-16f;
    unsigned short* ou = (unsigned short*)out1b;
    unsigned p0 = (unsigned)f2bf(acc0 / dd + bb.x) | ((unsigned)f2bf(acc1 / dd + bb.y) << 16);
    unsigned p1 = (unsigned)f2bf(acc2 / dd + bb.z) | ((unsigned)f2bf(acc3 / dd + bb.w) << 16);
    *(uint2*)&ou[(size_t)n * 64 + q * 4] = make_uint2(p0, p1);
}

// ---------------- layer-2 logits: aad2[n][j] = <out1[n], wsd[j]>, LDS-staged GEMV ----------------

__global__ __launch_bounds__(256) void k_att2(const __hip_bfloat16* out1b, const float* wsd,
                                              float* aad2) {
    __shared__ float t[64][65];
    int tid = threadIdx.x;
    int n0 = blockIdx.x * 64;
    const unsigned short* o1u = (const unsigned short*)out1b;
    #pragma unroll
    for (int l = 0; l < 4; l++) {
        int q = tid + l * 256;               // 1024 chunks of 4 bf16 in the 64x64 tile
        int r = q >> 4, c4 = q & 15;
        int n = n0 + r;
        uint2 v = make_uint2(0, 0);
        if (n < NN) v = *(const uint2*)&o1u[(size_t)n * 64 + c4 * 4];
        t[r][c4 * 4 + 0] = bfu((unsigned short)(v.x & 0xffff));
        t[r][c4 * 4 + 1] = bfu((unsigned short)(v.x >> 16));
        t[r][c4 * 4 + 2] = bfu((unsigned short)(v.y & 0xffff));
        t[r][c4 * 4 + 3] = bfu((unsigned short)(v.y >> 16));
    }
    __syncthreads();
    int lane = tid & 63;
    int j0 = __builtin_amdgcn_readfirstlane((tid >> 6) * 4);   // wave-uniform -> scalar wsd loads
    int n = n0 + lane;
    float a0 = 0.f, a1 = 0.f, a2 = 0.f, a3 = 0.f;
    #pragma unroll 8
    for (int k = 0; k < 64; k++) {
        float ov = t[lane][k];               // (lane+k)%32 banks: 2-way, free
        a0 += ov * wsd[(j0 + 0) * 64 + k];
        a1 += ov * wsd[(j0 + 1) * 64 + k];
        a2 += ov * wsd[(j0 + 2) * 64 + k];
        a3 += ov * wsd[(j0 + 3) * 64 + k];
    }
    if (n < NN) *(float4*)&aad2[(size_t)n * 16 + j0] = make_float4(a0, a1, a2, a3);
}

// ---------------- Layer-2 aggregation: 32 lanes/node (2 ch x 8 heads), 4-edge batches ----------------

__global__ __launch_bounds__(256) void k_agg2(const __hip_bfloat16* out1b, const __hip_bfloat16* we2b,
                                              const int* rowptr, const int* col,
                                              __hip_bfloat16* aggb, int n0, int n1) {
    int tid = threadIdx.x;
    int p = tid & 31;                          // channel pair within node
    int n = n0 + blockIdx.x * 8 + (tid >> 5);  // CHUNK = 8*6250 exact
    const unsigned short* o1u = (const unsigned short*)out1b;
    const unsigned short* weu = (const unsigned short*)we2b;
    int rs = rowptr[n], re = rowptr[n + 1];
    float den[8] = {}, a0[8] = {}, a1[8] = {};
    for (int eb = rs; eb < re; eb += 4) {
        int c4[4];
        #pragma unroll
        for (int j = 0; j < 4; j++) c4[j] = col[min(eb + j, re - 1)];   // batched col loads
        #pragma unroll
        for (int j = 0; j < 4; j++) {
            int e = min(eb + j, re - 1);
            uint4 wv = *(const uint4*)&weu[(size_t)e * 8];              // uniform per edge
            unsigned hv = *(const unsigned*)&o1u[(size_t)c4[j] * 64 + p * 2];
            float vmul = (eb + j < re) ? 1.f : 0.f;
            float h0 = bfu((unsigned short)(hv & 0xffff));
            float h1 = bfu((unsigned short)(hv >> 16));
            float wts[8] = {bfu((unsigned short)(wv.x & 0xffff)), bfu((unsigned short)(wv.x >> 16)),
                            bfu((unsigned short)(wv.y & 0xffff)), bfu((unsigned short)(wv.y >> 16)),
                            bfu((unsigned short)(wv.z & 0xffff)), bfu((unsigned short)(wv.z >> 16)),
                            bfu((unsigned short)(wv.w & 0xffff)), bfu((unsigned short)(wv.w >> 16))};
            #pragma unroll
            for (int hh = 0; hh < 8; hh++) {
                float ww = wts[hh] * vmul;
                den[hh] += ww;
                a0[hh] += ww * h0;
                a1[hh] += ww * h1;
            }
        }
    }
    size_t base = (size_t)(n - n0) * 512;
    unsigned short* au = (unsigned short*)aggb;
    #pragma unroll
    for (int hh = 0; hh < 8; hh++) {
        float dd = den[hh] + 1e-16f;
        unsigned pp = (unsigned)f2bf(a0[hh] / dd) | ((unsigned)f2bf(a1[hh] / dd) << 16);
        *(unsigned*)&au[base + hh * 64 + p * 2] = pp;
    }
}

// ---------------- gemm2 (bf16 MFMA): out2Tb[c][n] = bf16(0.125 * aggb[n] @ W2pT[c]^T + b2[c]) ----------------

__global__ __launch_bounds__(256) void k_gemm2(const __hip_bfloat16* aggb, const __hip_bfloat16* W2pT,
                                               const float* b2, __hip_bfloat16* out2Tb, int n0, int n1) {
    __shared__ float smem[4608];               // 18432 B: A_lds 64x72 bf16 | B_lds 64x72 bf16; reused as [64][66] f32
    unsigned short* A_lds = (unsigned short*)smem;           // [64][72] bf16, row 144 B
    unsigned short* B_lds = A_lds + 64 * 72;                 // [64][72] bf16
    const unsigned short* A_g = (const unsigned short*)aggb;
    const unsigned short* B_g = (const unsigned short*)W2pT;
    int tid = threadIdx.x;
    int w = tid >> 6, l = tid & 63;
    int m0 = blockIdx.x * 64;
    int rows = n1 - n0;
    f32x4_t acc[4] = {};                       // 4 col-tiles for this wave's 16-row band
    for (int k0 = 0; k0 < 512; k0 += 64) {
        #pragma unroll
        for (int ll = 0; ll < 2; ll++) {
            int u = tid + ll * 256;            // [0,512): r = row/col (64), seg = 8x8 bf16
            int r = u >> 3, seg = u & 7;
            uint4 va = make_uint4(0, 0, 0, 0);
            if (m0 + r < rows) va = *(const uint4*)&A_g[(size_t)(m0 + r) * 512 + k0 + seg * 8];
            *(uint4*)&A_lds[r * 72 + seg * 8] = va;
            *(uint4*)&B_lds[r * 72 + seg * 8] = *(const uint4*)&B_g[(size_t)r * 512 + k0 + seg * 8];
        }
        __syncthreads();
        #pragma unroll
        for (int kk = 0; kk < 2; kk++) {
            bf16x8_t a = *(const bf16x8_t*)&A_lds[(w * 16 + (l & 15)) * 72 + kk * 32 + (l >> 4) * 8];
            #pragma unroll
            for (int t = 0; t < 4; t++) {
                bf16x8_t bb = *(const bf16x8_t*)&B_lds[(t * 16 + (l & 15)) * 72 + kk * 32 + (l >> 4) * 8];
                acc[t] = __builtin_amdgcn_mfma_f32_16x16x32_bf16(a, bb, acc[t], 0, 0, 0);
            }
        }
        __syncthreads();
    }
    // epilogue: scale+bias into LDS f32 bounce, then coalesced transposed bf16 store
    #pragma unroll
    for (int t = 0; t < 4; t++) {
        int col_l = l & 15;
        float bias = b2[t * 16 + col_l];
        #pragma unroll
        for (int q = 0; q < 4; q++) {
            int row_l = (l >> 4) * 4 + q;      // C/D: col=lane&15, row=(lane>>4)*4+reg [m89]
            smem[(w * 16 + row_l) * 66 + t * 16 + col_l] = 0.125f * acc[t][q] + bias;
        }
    }
    __syncthreads();
    unsigned short* o2u = (unsigned short*)out2Tb;
    int ml = tid & 63, cr = tid >> 6;
    #pragma unroll
    for (int p = 0; p < 16; p++) {
        int c = p * 4 + cr;
        int gr = m0 + ml;
        if (gr < rows) o2u[(size_t)c * NN + (n0 + gr)] = f2bf(smem[ml * 66 + c]);
    }
}

// ---------------- MLP heads + CE: packed-h2 o tile in LDS, dot2 inner, 16+16 accumulators ----------------

__global__ __launch_bounds__(256) void k_mlp(const __hip_bfloat16* out2Tb,
                                             const unsigned* tswp, const float* tsb1,
                                             const float* tsw2, const float* tsb2,
                                             const unsigned* cwp, const float* cb1,
                                             const float* cw2, const float* cb2,
                                             const int* tst, const int* ctg, const unsigned char* msk,
                                             float* part) {
    __shared__ unsigned t2h[32 * 64];          // [kp][node_local] packed half2 (o[2kp], o[2kp+1])
    __shared__ float red[4][7][64];
    int tid = threadIdx.x;
    int lane = tid & 63;
    int w = tid >> 6;
    int n0 = blockIdx.x * 64;
    int nstage = n0 + lane; if (nstage >= NN) nstage = NN - 1;
    const unsigned short* o2u = (const unsigned short*)out2Tb;
    #pragma unroll
    for (int l = 0; l < 8; l++) {
        int kp = w * 8 + l;
        float e0 = bfu(o2u[(size_t)(2 * kp) * NN + nstage]);       // coalesced
        float e1 = bfu(o2u[(size_t)(2 * kp + 1) * NN + nstage]);
        t2h[kp * 64 + lane] = pkh2(e0, e1);
    }
    __syncthreads();

    int c0 = __builtin_amdgcn_readfirstlane(w * 16);          // wave-uniform -> scalar weight loads
    int n = n0 + lane;
    float vts[16], vcls[16];
    #pragma unroll
    for (int j = 0; j < 16; j++) { vts[j] = tsb1[c0 + j]; vcls[j] = cb1[c0 + j]; }
    for (int kp = 0; kp < 32; kp++) {
        unsigned ou = t2h[kp * 64 + lane];                    // conflict-free (stride 64, 1 row)
        h2_t ov = *(h2_t*)&ou;
        const unsigned* wt = &tswp[kp * 64 + c0];             // wave-uniform -> s_load_dwordx4
        const unsigned* wc = &cwp[kp * 64 + c0];
        #pragma unroll
        for (int j = 0; j < 16; j++) {
            unsigned wtv = wt[j], wcv = wc[j];
            vts[j]  = __builtin_amdgcn_fdot2(ov, *(h2_t*)&wtv, vts[j], false);
            vcls[j] = __builtin_amdgcn_fdot2(ov, *(h2_t*)&wcv, vcls[j], false);
        }
    }
    float lg[5] = {0.f, 0.f, 0.f, 0.f, 0.f};
    float lg2[2] = {0.f, 0.f};
    #pragma unroll
    for (int j = 0; j < 16; j++) {
        int c = c0 + j;
        float v = fmaxf(vts[j], 0.f);
        #pragma unroll
        for (int t = 0; t < 5; t++) lg[t] += v * tsw2[c * 5 + t];
        float v2 = fmaxf(vcls[j], 0.f);
        lg2[0] += v2 * cw2[c * 2];
        lg2[1] += v2 * cw2[c * 2 + 1];
    }
    #pragma unroll
    for (int t = 0; t < 5; t++) red[w][t][lane] = lg[t];
    red[w][5][lane] = lg2[0];
    red[w][6][lane] = lg2[1];
    __syncthreads();
    if (w == 0) {
        float tsl = 0.f, cll = 0.f, mval = 0.f;
        if (n < NN) {
            float L[5];
            #pragma unroll
            for (int t = 0; t < 5; t++)
                L[t] = red[0][t][lane] + red[1][t][lane] + red[2][t][lane] + red[3][t][lane] + tsb2[t];
            float mx = L[0];
            #pragma unroll
            for (int t = 1; t < 5; t++) mx = fmaxf(mx, L[t]);
            float se = 0.f;
            #pragma unroll
            for (int t = 0; t < 5; t++) se += __expf(L[t] - mx);
            int tg = tst[n];
            float pick = 0.f;
            #pragma unroll
            for (int t = 0; t < 5; t++) pick += (t == tg) ? L[t] : 0.f;
            tsl = mx + __logf(se) - pick;
            float C0 = red[0][5][lane] + red[1][5][lane] + red[2][5][lane] + red[3][5][lane] + cb2[0];
            float C1 = red[0][6][lane] + red[1][6][lane] + red[2][6][lane] + red[3][6][lane] + cb2[1];
            float mx2 = fmaxf(C0, C1);
            float lse2 = mx2 + __logf(__expf(C0 - mx2) + __expf(C1 - mx2));
            mval = msk[n] ? 1.f : 0.f;
            float pick2 = ctg[n] ? C1 : C0;
            cll = (lse2 - pick2) * mval;
        }
        #pragma unroll
        for (int off = 1; off < 64; off <<= 1) {
            tsl  += __shfl_xor(tsl, off);
            cll  += __shfl_xor(cll, off);
            mval += __shfl_xor(mval, off);
        }
        if (lane == 0) {
            part[blockIdx.x * 3 + 0] = tsl;
            part[blockIdx.x * 3 + 1] = cll;
            part[blockIdx.x * 3 + 2] = mval;
        }
    }
}

__global__ __launch_bounds__(256) void k_final(const float* part, float* out, int nb) {
    __shared__ float sm[3][256];
    int tid = threadIdx.x;
    float a = 0, b = 0, c = 0;
    for (int i = tid; i < nb; i += 256) { a += part[i*3]; b += part[i*3+1]; c += part[i*3+2]; }
    sm[0][tid] = a; sm[1][tid] = b; sm[2][tid] = c;
    __syncthreads();
    for (int s = 128; s > 0; s >>= 1) {
        if (tid < s) {
            sm[0][tid] += sm[0][tid + s];
            sm[1][tid] += sm[1][tid + s];
            sm[2][tid] += sm[2][tid + s];
        }
        __syncthreads();
    }
    if (tid == 0) out[0] = sm[1][0] / sm[2][0] + sm[0][0] / (float)NN;
}

// ---------------- host ----------------

extern "C" void kernel_launch(void* const* d_in, const int* in_sizes, int n_in,
                              void* d_out, int out_size, void* d_ws, size_t ws_size,
                              hipStream_t stream) {
    const float* x    = (const float*)d_in[0];
    const int*   ei   = (const int*)d_in[1];
    const int*   tst  = (const int*)d_in[2];
    const int*   ctg  = (const int*)d_in[3];
    const unsigned char* msk = (const unsigned char*)d_in[4];
    const float* W1   = (const float*)d_in[5];
    const float* a1s  = (const float*)d_in[6];
    const float* a1d  = (const float*)d_in[7];
    const float* b1   = (const float*)d_in[8];
    const float* W2   = (const float*)d_in[9];
    const float* a2s  = (const float*)d_in[10];
    const float* a2d  = (const float*)d_in[11];
    const float* b2   = (const float*)d_in[12];
    const float* tsw1 = (const float*)d_in[13];
    const float* tsb1 = (const float*)d_in[14];
    const float* tsw2 = (const float*)d_in[15];
    const float* tsb2 = (const float*)d_in[16];
    const float* cw1  = (const float*)d_in[17];
    const float* cb1  = (const float*)d_in[18];
    const float* cw2  = (const float*)d_in[19];
    const float* cb2  = (const float*)d_in[20];
    const int* srcE = ei;
    const int* dstE = ei + NE;

    char* ws = (char*)d_ws;
    size_t off = 0;
    auto alloc = [&](size_t b) { size_t o = off; off = (off + b + 255) & ~(size_t)255; return o; };
    int*   cnt    = (int*)(ws + alloc((size_t)NN * 4));
    int*   fill   = (int*)(ws + alloc((size_t)NN * 4));
    int*   rowptr = (int*)(ws + alloc((size_t)(NN + 1) * 4));
    int*   bsum   = (int*)(ws + alloc(128 * 4));
    int*   col    = (int*)(ws + alloc((size_t)NT * 4));
    int*   rowv   = (int*)(ws + alloc((size_t)NT * 4));
    float* aad1   = (float*)(ws + alloc((size_t)NN * 16 * 4));
    __hip_bfloat16* out1b = (__hip_bfloat16*)(ws + alloc((size_t)NN * 64 * 2));
    float* aad2   = (float*)(ws + alloc((size_t)NN * 16 * 4));
    float* wsd    = (float*)(ws + alloc(1024 * 4));
    __hip_bfloat16* W2pT  = (__hip_bfloat16*)(ws + alloc(32768 * 2));
    unsigned* tswp = (unsigned*)(ws + alloc(2048 * 4));
    unsigned* cwp  = (unsigned*)(ws + alloc(2048 * 4));
    unsigned* W1pT = (unsigned*)(ws + alloc(6144 * 4));
    float* zbuf   = (float*)(ws + alloc(256 * 4));
    __hip_bfloat16* out2Tb = (__hip_bfloat16*)(ws + alloc((size_t)NN * 64 * 2));
    __hip_bfloat16* h1b   = (__hip_bfloat16*)(ws + alloc((size_t)NN * 64 * 2));
    __hip_bfloat16* aggb  = (__hip_bfloat16*)(ws + alloc((size_t)CHUNK * 512 * 2));
    __hip_bfloat16* web   = (__hip_bfloat16*)(ws + alloc((size_t)NT * 8 * 2));
    float* part   = (float*)(ws + alloc((size_t)NODEB * 3 * 4));
    (void)ws_size; (void)in_sizes; (void)n_in; (void)out_size;

    int nb_scan = (NN + 1023) / 1024;  // 98

    k_misc<<<MISCGRID, 256, 0, stream>>>(W2, a2s, a2d, wsd, W2pT, cnt, fill,
                                         tsw1, cw1, tswp, cwp, W1, W1pT, zbuf);
    k_count<<<(NE + 255) / 256, 256, 0, stream>>>(dstE, cnt);
    k_scanA<<<nb_scan, 256, 0, stream>>>(cnt, rowptr, bsum);
    k_scanB<<<1, 64, 0, stream>>>(bsum, nb_scan);
    k_scanC<<<(NN + 255) / 256, 256, 0, stream>>>(bsum, rowptr);
    k_fill<<<(NT + 255) / 256, 256, 0, stream>>>(srcE, dstE, rowptr, fill, col, rowv);

    k_gemm1<<<NODEB, 256, 0, stream>>>(x, W1pT, a1s, a1d, zbuf, h1b, aad1);
    k_edgew<<<(NT + 255) / 256, 256, 0, stream>>>(aad1, col, rowv, web);
    k_agg1<<<NN / 16, 256, 0, stream>>>(h1b, web, rowptr, col, b1, out1b);
    k_att2<<<NODEB, 256, 0, stream>>>(out1b, wsd, aad2);
    k_edgew<<<(NT + 255) / 256, 256, 0, stream>>>(aad2, col, rowv, web);

    for (int c = 0; c < 2; c++) {
        int n0 = c * CHUNK, n1 = n0 + CHUNK;
        k_agg2<<<CHUNK / 8, 256, 0, stream>>>(out1b, web, rowptr, col, aggb, n0, n1);
        k_gemm2<<<(CHUNK + 63) / 64, 256, 0, stream>>>(aggb, W2pT, b2, out2Tb, n0, n1);
    }

    k_mlp<<<NODEB, 256, 0, stream>>>(out2Tb, tswp, tsb1, tsw2, tsb2,
                                     cwp, cb1, cw2, cb2, tst, ctg, msk, part);
    k_final<<<1, 256, 0, stream>>>(part, (float*)d_out, NODEB);
}

// Round 4
// 196.210 us; speedup vs baseline: 1.2514x; 1.0883x over previous
//
#include <hip/hip_runtime.h>
#include <hip/hip_bf16.h>

#define NN 100000      // nodes
#define NE 200000      // edges (without self loops)
#define NT (NE + NN)   // total edges incl self loops
#define DIN 165
#define PREPB 128
#define INITB 391
#define PACKB 32       // 8192 threads: wB [128 cols][64 k] bf16 pack
#define W1PB 24        // W1 f16 [c][192] pack: 6144 u32
#define MISCGRID (PREPB + INITB + PACKB + W1PB)
#define NODEB 1563     // ceil(NN/64) blocks (64-node tiles)
#define XDW ((size_t)NN * DIN)   // total x dwords (16.5M, divisible by 4)
#define G1ROWS 32      // gemm1 rows/block (NN = 3125*32 exact)
#define G1NDMA 21      // 21 KiB staged per 32-row tile (need 21120B, have 21504B)

typedef __attribute__((ext_vector_type(8))) short bf16x8_t;
typedef __attribute__((ext_vector_type(4))) float f32x4_t;
typedef _Float16 h2_t __attribute__((ext_vector_type(2)));
typedef _Float16 f16x8_t __attribute__((ext_vector_type(8)));

#define AS1 __attribute__((address_space(1)))
#define AS3 __attribute__((address_space(3)))

static __device__ __forceinline__ unsigned short f2bf(float f) {
    __hip_bfloat16 b = __float2bfloat16(f);
    return *(unsigned short*)&b;
}
static __device__ __forceinline__ float bfu(unsigned short u) {
    __hip_bfloat16 b = *(__hip_bfloat16*)&u;
    return __bfloat162float(b);
}
static __device__ __forceinline__ unsigned pkh2(float a, float b) {
    h2_t v; v[0] = (_Float16)a; v[1] = (_Float16)b;
    return *(unsigned*)&v;
}

// ---------------- merged prep: W2pT/wsd | CSR init | mlp wB pack | W1 f16 pack ----------------

__global__ __launch_bounds__(256) void k_misc(const float* W2, const float* a2s, const float* a2d,
                                              float* wsd, __hip_bfloat16* W2pT,
                                              int* cnt, int* fill,
                                              const float* tsw1, const float* cw1,
                                              __hip_bfloat16* wB,
                                              const float* W1, unsigned* W1pT, float* zbuf) {
    int b = blockIdx.x;
    int tid = threadIdx.x;
    if (b < PREPB) {
        int i = b * 256 + tid;                 // [0, 32768)
        // W2pT[c][j] = bf16(W2[kk*512 + h*64 + c]),  j = h*64 + kk
        int c = i >> 9, j = i & 511;
        int hh = j >> 6, kk = j & 63;
        W2pT[i] = __float2bfloat16(W2[kk * 512 + hh * 64 + c]);
        if (b == 0) zbuf[tid] = 0.f;           // zero source for gemm1 DMA padding
        if (i < 512) {
            int h = i >> 6, k = i & 63;
            float s = 0.f, d = 0.f;
            for (int cc = 0; cc < 64; cc++) {
                float w = W2[k * 512 + h * 64 + cc];
                s += w * a2s[h * 64 + cc];
                d += w * a2d[h * 64 + cc];
            }
            wsd[i] = s; wsd[512 + i] = d;
        }
    } else if (b < PREPB + INITB) {
        int i = (b - PREPB) * 256 + tid;
        if (i < NN) { cnt[i] = 0; fill[i] = 0; }
    } else if (b < PREPB + INITB + PACKB) {
        int i = (b - PREPB - INITB) * 256 + tid;  // [0, 8192): c*64 + k
        if (i < 8192) {
            int c = i >> 6, k = i & 63;
            float v = (c < 64) ? tsw1[k * 64 + c] : cw1[k * 64 + (c - 64)];
            wB[i] = __float2bfloat16(v);          // [128 cols][64 k]: ts cols 0-63, cls 64-127
        }
    } else {
        int i = (b - PREPB - INITB - PACKB) * 256 + tid;  // [0, 6144): c*96 + kp
        if (i < 6144) {
            int c = i / 96, kp = i - c * 96;
            int k = 2 * kp;
            float f0 = (k < DIN) ? W1[k * 64 + c] : 0.f;
            float f1 = (k + 1 < DIN) ? W1[(k + 1) * 64 + c] : 0.f;
            W1pT[i] = pkh2(f0, f1);               // [c][96] u32 = [c][192] f16, zero-padded K
        }
    }
}

// ---------------- CSR build ----------------

__global__ __launch_bounds__(256) void k_count(const int* dstE, int* cnt) {
    int e = blockIdx.x * 256 + threadIdx.x;
    if (e < NE) atomicAdd(&cnt[dstE[e]], 1);
}

__global__ __launch_bounds__(256) void k_scanA(const int* cnt, int* rowptr, int* bsum) {
    __shared__ int sm[256];
    int t = threadIdx.x;
    int base = blockIdx.x * 1024;
    int v[4]; int s = 0;
    for (int i = 0; i < 4; i++) {
        int idx = base + t * 4 + i;
        v[i] = (idx < NN) ? (cnt[idx] + 1) : 0;
        s += v[i];
    }
    sm[t] = s; __syncthreads();
    for (int off = 1; off < 256; off <<= 1) {
        int x = (t >= off) ? sm[t - off] : 0;
        __syncthreads();
        sm[t] += x;
        __syncthreads();
    }
    int run = sm[t] - s;
    for (int i = 0; i < 4; i++) {
        run += v[i];
        int idx = base + t * 4 + i;
        if (idx < NN) rowptr[idx + 1] = run;
    }
    if (t == 255) bsum[blockIdx.x] = sm[255];
}

__global__ __launch_bounds__(64) void k_scanB(int* bsum, int nb) {
    int lane = threadIdx.x;
    int v0 = (lane < nb) ? bsum[lane] : 0;
    int v1 = (64 + lane < nb) ? bsum[64 + lane] : 0;
    int s0 = v0;
    for (int off = 1; off < 64; off <<= 1) { int t = __shfl_up(s0, off); if (lane >= off) s0 += t; }
    int tot0 = __shfl(s0, 63);
    int s1 = v1;
    for (int off = 1; off < 64; off <<= 1) { int t = __shfl_up(s1, off); if (lane >= off) s1 += t; }
    if (lane < nb) bsum[lane] = s0 - v0;
    if (64 + lane < nb) bsum[64 + lane] = tot0 + s1 - v1;
}

__global__ __launch_bounds__(256) void k_scanC(const int* bsum, int* rowptr) {
    int i = blockIdx.x * 256 + threadIdx.x;
    if (i < NN) rowptr[i + 1] += bsum[i >> 10];
    if (i == 0) rowptr[0] = 0;
}

__global__ __launch_bounds__(256) void k_fill(const int* srcE, const int* dstE,
                                              const int* rowptr, int* fill, int* col, int* rowv) {
    int i = blockIdx.x * 256 + threadIdx.x;
    if (i >= NT) return;
    int s, d;
    if (i < NE) { s = srcE[i]; d = dstE[i]; }
    else        { s = i - NE; d = s; }        // self loop
    int p = rowptr[d] + atomicAdd(&fill[d], 1);
    col[p] = s;
    rowv[p] = d;
}

// ---------------- Layer 1 GEMM (f16 MFMA): 32-row tiles, 128 thr, burst DMA, 7 blocks/CU ----------------

__global__ __launch_bounds__(128) void k_gemm1(const float* x, const unsigned* W1pT,
                                               const float* att_s, const float* att_d,
                                               const float* zsrc,
                                               __hip_bfloat16* h1b, float* aad1) {
    __shared__ float X[G1NDMA * 256];          // 21504 B staged tile; reused as h1 bounce
    int tid = threadIdx.x;
    int l = tid & 63, w = tid >> 6;            // w in {0,1}
    int n0 = blockIdx.x * G1ROWS;
    int frow = l & 15, kg = l >> 4;

    // burst-stage whole 32x165 f32 tile (contiguous, 16B-aligned: n0*660B)
    size_t tb = (size_t)n0 * DIN;
    for (int i = w; i < G1NDMA; i += 2) {
        size_t gd = tb + (size_t)i * 256 + (size_t)l * 4;
        const float* g = (gd + 4 <= XDW) ? (x + gd) : (zsrc + l * 4);
        __builtin_amdgcn_global_load_lds((const AS1 float*)g,
                                         (AS3 float*)(X + i * 256), 16, 0, 0);
    }
    // preload ALL B fragments (24 KB W1pT, L2-resident) while DMA flies
    uint4 B[6][4];
    #pragma unroll
    for (int s = 0; s < 6; s++)
        #pragma unroll
        for (int t = 0; t < 4; t++)
            B[s][t] = *(const uint4*)&W1pT[(t * 16 + frow) * 96 + s * 16 + kg * 4];
    __syncthreads();                           // drains vmcnt: tile + B ready

    // 6 MFMA steps, all operands local (over-read past k=165 annihilated by W1pT zero-pad)
    f32x4_t acc[4] = {};
    int rbase = (w * 16 + frow) * DIN + kg * 8;
    #pragma unroll
    for (int s = 0; s < 6; s++) {
        f16x8_t av;
        #pragma unroll
        for (int j = 0; j < 8; j++) av[j] = (_Float16)X[rbase + s * 32 + j];
        #pragma unroll
        for (int t = 0; t < 4; t++)
            acc[t] = __builtin_amdgcn_mfma_f32_16x16x32_f16(av, *(f16x8_t*)&B[s][t], acc[t], 0, 0, 0);
    }

    // attention partials (C/D: col=l&15 -> c=t*16+frow, row=kg*4+q [m89])
    int nw = n0 + w * 16;
    float asv[4], adv[4];
    #pragma unroll
    for (int t = 0; t < 4; t++) {
        int c = t * 16 + frow;
        asv[t] = att_s[c]; adv[t] = att_d[c];
    }
    int hb = (l >> 3) & 1;
    #pragma unroll
    for (int q = 0; q < 4; q++) {
        int n = nw + kg * 4 + q;
        #pragma unroll
        for (int t = 0; t < 4; t++) {
            float sv = acc[t][q] * asv[t];
            float dv = acc[t][q] * adv[t];
            sv += __shfl_xor(sv, 1); sv += __shfl_xor(sv, 2); sv += __shfl_xor(sv, 4);
            dv += __shfl_xor(dv, 1); dv += __shfl_xor(dv, 2); dv += __shfl_xor(dv, 4);
            if ((l & 7) == 0) {
                int h = t * 2 + hb;
                aad1[(size_t)n * 16 + h]     = sv;
                aad1[(size_t)n * 16 + 8 + h] = dv;
            }
        }
    }

    // h1 via LDS bounce -> coalesced 32B/lane stores
    __syncthreads();
    unsigned short* Hw = (unsigned short*)X + w * 1152;    // per-wave [16][72] bf16
    #pragma unroll
    for (int t = 0; t < 4; t++)
        #pragma unroll
        for (int q = 0; q < 4; q++)
            Hw[(kg * 4 + q) * 72 + t * 16 + frow] = f2bf(acc[t][q]);
    int rr = l >> 2, cc = l & 3;
    int n2 = nw + rr;
    unsigned short* dst = (unsigned short*)h1b + (size_t)n2 * 64 + cc * 16;
    *(uint4*)dst       = *(const uint4*)&Hw[rr * 72 + cc * 16];
    *(uint4*)(dst + 8) = *(const uint4*)&Hw[rr * 72 + cc * 16 + 8];
}

// ---------------- per-edge softmax numerators (bf16) ----------------

__global__ __launch_bounds__(256) void k_edgew(const float* aad, const int* col, const int* rowv,
                                               __hip_bfloat16* web) {
    int e = blockIdx.x * 256 + threadIdx.x;
    if (e >= NT) return;
    int s = col[e], d = rowv[e];
    float4 s0 = *(const float4*)&aad[(size_t)s * 16];
    float4 s1 = *(const float4*)&aad[(size_t)s * 16 + 4];
    float4 dd0 = *(const float4*)&aad[(size_t)d * 16 + 8];
    float4 dd1 = *(const float4*)&aad[(size_t)d * 16 + 12];
    float as[8] = {s0.x, s0.y, s0.z, s0.w, s1.x, s1.y, s1.z, s1.w};
    float ad[8] = {dd0.x, dd0.y, dd0.z, dd0.w, dd1.x, dd1.y, dd1.z, dd1.w};
    unsigned p[4];
    #pragma unroll
    for (int q = 0; q < 4; q++) {
        float a0 = as[2*q]   + ad[2*q];
        float a1 = as[2*q+1] + ad[2*q+1];
        a0 = a0 > 0.f ? a0 : 0.2f * a0;
        a1 = a1 > 0.f ? a1 : 0.2f * a1;
        p[q] = (unsigned)f2bf(__expf(a0)) | ((unsigned)f2bf(__expf(a1)) << 16);
    }
    *(uint4*)&web[(size_t)e * 8] = make_uint4(p[0], p[1], p[2], p[3]);
}

// ---------------- Layer-1 aggregation: 16 lanes/node (4 ch each), 4-edge batches ----------------

__global__ __launch_bounds__(256) void k_agg1(const __hip_bfloat16* h1b, const __hip_bfloat16* we1b,
                                              const int* rowptr, const int* col,
                                              const float* b1, __hip_bfloat16* out1b) {
    int tid = threadIdx.x;
    int q = tid & 15;                          // channel quad within node
    int n = blockIdx.x * 16 + (tid >> 4);     // NN = 16*6250 exact
    int hq = q >> 1;                           // head of channels 4q..4q+3
    const unsigned short* h1u = (const unsigned short*)h1b;
    const unsigned short* weu = (const unsigned short*)we1b;
    int rs = rowptr[n], re = rowptr[n + 1];
    float acc0 = 0.f, acc1 = 0.f, acc2 = 0.f, acc3 = 0.f, den = 0.f;
    for (int eb = rs; eb < re; eb += 4) {
        int c4[4];
        #pragma unroll
        for (int j = 0; j < 4; j++) c4[j] = col[min(eb + j, re - 1)];   // batched col loads
        #pragma unroll
        for (int j = 0; j < 4; j++) {
            int e = min(eb + j, re - 1);
            float wv = bfu(weu[(size_t)e * 8 + hq]);
            wv = (eb + j < re) ? wv : 0.f;                              // predicate after load
            uint2 hv = *(const uint2*)&h1u[(size_t)c4[j] * 64 + q * 4]; // batched row gathers
            den  += wv;
            acc0 += wv * bfu((unsigned short)(hv.x & 0xffff));
            acc1 += wv * bfu((unsigned short)(hv.x >> 16));
            acc2 += wv * bfu((unsigned short)(hv.y & 0xffff));
            acc3 += wv * bfu((unsigned short)(hv.y >> 16));
        }
    }
    float4 bb = *(const float4*)&b1[q * 4];
    float dd = den + 1e-16f;
    unsigned short* ou = (unsigned short*)out1b;
    unsigned p0 = (unsigned)f2bf(acc0 / dd + bb.x) | ((unsigned)f2bf(acc1 / dd + bb.y) << 16);
    unsigned p1 = (unsigned)f2bf(acc2 / dd + bb.z) | ((unsigned)f2bf(acc3 / dd + bb.w) << 16);
    *(uint2*)&ou[(size_t)n * 64 + q * 4] = make_uint2(p0, p1);
}

// ---------------- layer-2 logits: aad2[n][j] = <out1[n], wsd[j]>, LDS-staged GEMV ----------------

__global__ __launch_bounds__(256) void k_att2(const __hip_bfloat16* out1b, const float* wsd,
                                              float* aad2) {
    __shared__ float t[64][65];
    int tid = threadIdx.x;
    int n0 = blockIdx.x * 64;
    const unsigned short* o1u = (const unsigned short*)out1b;
    #pragma unroll
    for (int l = 0; l < 4; l++) {
        int q = tid + l * 256;               // 1024 chunks of 4 bf16 in the 64x64 tile
        int r = q >> 4, c4 = q & 15;
        int n = n0 + r;
        uint2 v = make_uint2(0, 0);
        if (n < NN) v = *(const uint2*)&o1u[(size_t)n * 64 + c4 * 4];
        t[r][c4 * 4 + 0] = bfu((unsigned short)(v.x & 0xffff));
        t[r][c4 * 4 + 1] = bfu((unsigned short)(v.x >> 16));
        t[r][c4 * 4 + 2] = bfu((unsigned short)(v.y & 0xffff));
        t[r][c4 * 4 + 3] = bfu((unsigned short)(v.y >> 16));
    }
    __syncthreads();
    int lane = tid & 63;
    int j0 = __builtin_amdgcn_readfirstlane((tid >> 6) * 4);   // wave-uniform -> scalar wsd loads
    int n = n0 + lane;
    float a0 = 0.f, a1 = 0.f, a2 = 0.f, a3 = 0.f;
    #pragma unroll 8
    for (int k = 0; k < 64; k++) {
        float ov = t[lane][k];               // (lane+k)%32 banks: 2-way, free
        a0 += ov * wsd[(j0 + 0) * 64 + k];
        a1 += ov * wsd[(j0 + 1) * 64 + k];
        a2 += ov * wsd[(j0 + 2) * 64 + k];
        a3 += ov * wsd[(j0 + 3) * 64 + k];
    }
    if (n < NN) *(float4*)&aad2[(size_t)n * 16 + j0] = make_float4(a0, a1, a2, a3);
}

// ---------------- FUSED layer-2: agg2 + gemm2 + mlp heads + CE, one kernel per 64-node tile ----------------
// Phase A: aggregate [64 nodes][512=h*64+c] bf16 into LDS (16B-block XOR swizzle ^ (row&7)).
// Phase B: W2 MFMA k-loop (A from LDS, B staged per k0 from L2-resident W2pT).
// Phase C: o2 = 0.125*acc + b2 -> LDS bf16 [64][72]; mlp1 MFMA vs wB [128 cols][64 k].
// Phase D: bias+relu+w2 projections per lane, 16-lane shfl reduce, CE, block partial -> part.

__global__ __launch_bounds__(256) void k_l2f(const __hip_bfloat16* out1b, const __hip_bfloat16* we2b,
                                             const int* rowptr, const int* col,
                                             const __hip_bfloat16* W2pT, const float* b2,
                                             const __hip_bfloat16* wB,
                                             const float* tsb1, const float* cb1,
                                             const float* tsw2, const float* tsb2,
                                             const float* cw2, const float* cb2,
                                             const int* tst, const int* ctg, const unsigned char* msk,
                                             float* part) {
    __shared__ unsigned short Ax[64 * 512];    // 64 KB agg tile (swizzled); front reused as o2L
    __shared__ unsigned short Bl[64 * 72];     // 9.2 KB B stage
    __shared__ float red[4][3];
    int tid = threadIdx.x;
    int l = tid & 63, w = tid >> 6;
    int n0 = blockIdx.x * 64;
    int frow = l & 15, kg = l >> 4;

    // ---- phase A: 16 lanes/node (4 ch x 8 heads), 4 passes of 16 nodes ----
    const unsigned short* o1u = (const unsigned short*)out1b;
    const unsigned short* weu = (const unsigned short*)we2b;
    int q4 = tid & 15;
    #pragma unroll 1
    for (int pass = 0; pass < 4; pass++) {
        int j = pass * 16 + (tid >> 4);
        int n = n0 + j;
        int rs = 0, re = 0;
        if (n < NN) { rs = rowptr[n]; re = rowptr[n + 1]; }
        float acc[8][4];
        float den[8];
        #pragma unroll
        for (int h = 0; h < 8; h++) {
            den[h] = 0.f;
            #pragma unroll
            for (int c = 0; c < 4; c++) acc[h][c] = 0.f;
        }
        for (int eb = rs; eb < re; eb += 4) {
            int c4[4];
            #pragma unroll
            for (int jj = 0; jj < 4; jj++) c4[jj] = col[min(eb + jj, re - 1)];
            #pragma unroll
            for (int jj = 0; jj < 4; jj++) {
                int e = min(eb + jj, re - 1);
                uint4 wv = *(const uint4*)&weu[(size_t)e * 8];           // uniform per node-group
                uint2 hv = *(const uint2*)&o1u[(size_t)c4[jj] * 64 + q4 * 4];
                float vm = (eb + jj < re) ? 1.f : 0.f;
                float hc0 = bfu((unsigned short)(hv.x & 0xffff));
                float hc1 = bfu((unsigned short)(hv.x >> 16));
                float hc2 = bfu((unsigned short)(hv.y & 0xffff));
                float hc3 = bfu((unsigned short)(hv.y >> 16));
                float wt[8] = {bfu((unsigned short)(wv.x & 0xffff)), bfu((unsigned short)(wv.x >> 16)),
                               bfu((unsigned short)(wv.y & 0xffff)), bfu((unsigned short)(wv.y >> 16)),
                               bfu((unsigned short)(wv.z & 0xffff)), bfu((unsigned short)(wv.z >> 16)),
                               bfu((unsigned short)(wv.w & 0xffff)), bfu((unsigned short)(wv.w >> 16))};
                #pragma unroll
                for (int h = 0; h < 8; h++) {
                    float ww = wt[h] * vm;
                    den[h] += ww;
                    acc[h][0] += ww * hc0;
                    acc[h][1] += ww * hc1;
                    acc[h][2] += ww * hc2;
                    acc[h][3] += ww * hc3;
                }
            }
        }
        #pragma unroll
        for (int h = 0; h < 8; h++) {
            float dd = den[h] + 1e-16f;
            unsigned lo = (unsigned)f2bf(acc[h][0] / dd) | ((unsigned)f2bf(acc[h][1] / dd) << 16);
            unsigned hi = (unsigned)f2bf(acc[h][2] / dd) | ((unsigned)f2bf(acc[h][3] / dd) << 16);
            int blk = (h * 8 + (q4 >> 1)) ^ (j & 7);                     // 16B-block swizzle
            *(uint2*)&Ax[j * 512 + blk * 8 + (q4 & 1) * 4] = make_uint2(lo, hi);
        }
    }
    __syncthreads();

    // ---- phase B: gemm2 MFMA (rows = nodes, cols = 64 out ch, K = 512) ----
    const unsigned short* B_g = (const unsigned short*)W2pT;
    f32x4_t gacc[4] = {};
    for (int k0 = 0; k0 < 512; k0 += 64) {
        #pragma unroll
        for (int ll = 0; ll < 2; ll++) {
            int u = tid + ll * 256;            // [0,512): r = out col, seg = 8x8 bf16
            int r = u >> 3, seg = u & 7;
            *(uint4*)&Bl[r * 72 + seg * 8] = *(const uint4*)&B_g[(size_t)r * 512 + k0 + seg * 8];
        }
        __syncthreads();
        #pragma unroll
        for (int kk = 0; kk < 2; kk++) {
            int blk = ((k0 >> 3) + kk * 4 + kg) ^ (frow & 7);
            bf16x8_t a = *(const bf16x8_t*)&Ax[(w * 16 + frow) * 512 + blk * 8];
            #pragma unroll
            for (int t = 0; t < 4; t++) {
                bf16x8_t bb = *(const bf16x8_t*)&Bl[(t * 16 + frow) * 72 + kk * 32 + kg * 8];
                gacc[t] = __builtin_amdgcn_mfma_f32_16x16x32_bf16(a, bb, gacc[t], 0, 0, 0);
            }
        }
        __syncthreads();
    }

    // ---- phase C: o2 bf16 -> LDS (reuse Ax front), then mlp1 MFMA vs wB ----
    unsigned short* o2L = Ax;                  // [64][72] bf16
    #pragma unroll
    for (int t = 0; t < 4; t++) {
        float bias = b2[t * 16 + frow];
        #pragma unroll
        for (int q = 0; q < 4; q++)
            o2L[(w * 16 + kg * 4 + q) * 72 + t * 16 + frow] = f2bf(0.125f * gacc[t][q] + bias);
    }
    __syncthreads();
    const unsigned short* wBu = (const unsigned short*)wB;
    f32x4_t a2c[8] = {};
    #pragma unroll
    for (int kk = 0; kk < 2; kk++) {
        bf16x8_t a2 = *(const bf16x8_t*)&o2L[(w * 16 + frow) * 72 + kk * 32 + kg * 8];
        #pragma unroll
        for (int t2 = 0; t2 < 8; t2++) {
            bf16x8_t b2f = *(const bf16x8_t*)&wBu[(t2 * 16 + frow) * 64 + kk * 32 + kg * 8];
            a2c[t2] = __builtin_amdgcn_mfma_f32_16x16x32_bf16(a2, b2f, a2c[t2], 0, 0, 0);
        }
    }

    // ---- phase D: bias+relu+second-layer projections, reduce, CE ----
    float lg[4][5]; float lc[4][2];
    #pragma unroll
    for (int q = 0; q < 4; q++) {
        #pragma unroll
        for (int t = 0; t < 5; t++) lg[q][t] = 0.f;
        lc[q][0] = 0.f; lc[q][1] = 0.f;
    }
    #pragma unroll
    for (int t2 = 0; t2 < 4; t2++) {
        int c = t2 * 16 + frow;
        float bb = tsb1[c];
        float w0 = tsw2[c * 5 + 0], w1 = tsw2[c * 5 + 1], w2 = tsw2[c * 5 + 2],
              w3 = tsw2[c * 5 + 3], w4 = tsw2[c * 5 + 4];
        #pragma unroll
        for (int q = 0; q < 4; q++) {
            float v = fmaxf(a2c[t2][q] + bb, 0.f);
            lg[q][0] += v * w0; lg[q][1] += v * w1; lg[q][2] += v * w2;
            lg[q][3] += v * w3; lg[q][4] += v * w4;
        }
    }
    #pragma unroll
    for (int t2 = 0; t2 < 4; t2++) {
        int c = t2 * 16 + frow;
        float bb = cb1[c];
        float u0 = cw2[c * 2], u1 = cw2[c * 2 + 1];
        #pragma unroll
        for (int q = 0; q < 4; q++) {
            float v = fmaxf(a2c[t2 + 4][q] + bb, 0.f);
            lc[q][0] += v * u0; lc[q][1] += v * u1;
        }
    }
    #pragma unroll
    for (int q = 0; q < 4; q++) {
        #pragma unroll
        for (int t = 0; t < 5; t++) {
            lg[q][t] += __shfl_xor(lg[q][t], 1);
            lg[q][t] += __shfl_xor(lg[q][t], 2);
            lg[q][t] += __shfl_xor(lg[q][t], 4);
            lg[q][t] += __shfl_xor(lg[q][t], 8);
        }
        #pragma unroll
        for (int t = 0; t < 2; t++) {
            lc[q][t] += __shfl_xor(lc[q][t], 1);
            lc[q][t] += __shfl_xor(lc[q][t], 2);
            lc[q][t] += __shfl_xor(lc[q][t], 4);
            lc[q][t] += __shfl_xor(lc[q][t], 8);
        }
    }
    float tsl = 0.f, cll = 0.f, mval = 0.f;
    if (frow == 0) {
        #pragma unroll
        for (int q = 0; q < 4; q++) {
            int n = n0 + w * 16 + kg * 4 + q;
            if (n < NN) {
                float L[5];
                #pragma unroll
                for (int t = 0; t < 5; t++) L[t] = lg[q][t] + tsb2[t];
                float mx = fmaxf(fmaxf(fmaxf(L[0], L[1]), fmaxf(L[2], L[3])), L[4]);
                float se = 0.f;
                #pragma unroll
                for (int t = 0; t < 5; t++) se += __expf(L[t] - mx);
                int tg = tst[n];
                float pick = 0.f;
                #pragma unroll
                for (int t = 0; t < 5; t++) pick += (t == tg) ? L[t] : 0.f;
                tsl += mx + __logf(se) - pick;
                float C0 = lc[q][0] + cb2[0];
                float C1 = lc[q][1] + cb2[1];
                float mx2 = fmaxf(C0, C1);
                float lse2 = mx2 + __logf(__expf(C0 - mx2) + __expf(C1 - mx2));
                float mv = msk[n] ? 1.f : 0.f;
                float pick2 = ctg[n] ? C1 : C0;
                cll += (lse2 - pick2) * mv;
                mval += mv;
            }
        }
    }
    #pragma unroll
    for (int off = 1; off < 64; off <<= 1) {
        tsl  += __shfl_xor(tsl, off);
        cll  += __shfl_xor(cll, off);
        mval += __shfl_xor(mval, off);
    }
    if (l == 0) { red[w][0] = tsl; red[w][1] = cll; red[w][2] = mval; }
    __syncthreads();
    if (tid == 0) {
        part[blockIdx.x * 3 + 0] = red[0][0] + red[1][0] + red[2][0] + red[3][0];
        part[blockIdx.x * 3 + 1] = red[0][1] + red[1][1] + red[2][1] + red[3][1];
        part[blockIdx.x * 3 + 2] = red[0][2] + red[1][2] + red[2][2] + red[3][2];
    }
}

__global__ __launch_bounds__(256) void k_final(const float* part, float* out, int nb) {
    __shared__ float sm[3][256];
    int tid = threadIdx.x;
    float a = 0, b = 0, c = 0;
    for (int i = tid; i < nb; i += 256) { a += part[i*3]; b += part[i*3+1]; c += part[i*3+2]; }
    sm[0][tid] = a; sm[1][tid] = b; sm[2][tid] = c;
    __syncthreads();
    for (int s = 128; s > 0; s >>= 1) {
        if (tid < s) {
            sm[0][tid] += sm[0][tid + s];
            sm[1][tid] += sm[1][tid + s];
            sm[2][tid] += sm[2][tid + s];
        }
        __syncthreads();
    }
    if (tid == 0) out[0] = sm[1][0] / sm[2][0] + sm[0][0] / (float)NN;
}

// ---------------- host ----------------

extern "C" void kernel_launch(void* const* d_in, const int* in_sizes, int n_in,
                              void* d_out, int out_size, void* d_ws, size_t ws_size,
                              hipStream_t stream) {
    const float* x    = (const float*)d_in[0];
    const int*   ei   = (const int*)d_in[1];
    const int*   tst  = (const int*)d_in[2];
    const int*   ctg  = (const int*)d_in[3];
    const unsigned char* msk = (const unsigned char*)d_in[4];
    const float* W1   = (const float*)d_in[5];
    const float* a1s  = (const float*)d_in[6];
    const float* a1d  = (const float*)d_in[7];
    const float* b1   = (const float*)d_in[8];
    const float* W2   = (const float*)d_in[9];
    const float* a2s  = (const float*)d_in[10];
    const float* a2d  = (const float*)d_in[11];
    const float* b2   = (const float*)d_in[12];
    const float* tsw1 = (const float*)d_in[13];
    const float* tsb1 = (const float*)d_in[14];
    const float* tsw2 = (const float*)d_in[15];
    const float* tsb2 = (const float*)d_in[16];
    const float* cw1  = (const float*)d_in[17];
    const float* cb1  = (const float*)d_in[18];
    const float* cw2  = (const float*)d_in[19];
    const float* cb2  = (const float*)d_in[20];
    const int* srcE = ei;
    const int* dstE = ei + NE;

    char* ws = (char*)d_ws;
    size_t off = 0;
    auto alloc = [&](size_t b) { size_t o = off; off = (off + b + 255) & ~(size_t)255; return o; };
    int*   cnt    = (int*)(ws + alloc((size_t)NN * 4));
    int*   fill   = (int*)(ws + alloc((size_t)NN * 4));
    int*   rowptr = (int*)(ws + alloc((size_t)(NN + 1) * 4));
    int*   bsum   = (int*)(ws + alloc(128 * 4));
    int*   col    = (int*)(ws + alloc((size_t)NT * 4));
    int*   rowv   = (int*)(ws + alloc((size_t)NT * 4));
    float* aad1   = (float*)(ws + alloc((size_t)NN * 16 * 4));
    __hip_bfloat16* out1b = (__hip_bfloat16*)(ws + alloc((size_t)NN * 64 * 2));
    float* aad2   = (float*)(ws + alloc((size_t)NN * 16 * 4));
    float* wsd    = (float*)(ws + alloc(1024 * 4));
    __hip_bfloat16* W2pT  = (__hip_bfloat16*)(ws + alloc(32768 * 2));
    __hip_bfloat16* wB    = (__hip_bfloat16*)(ws + alloc(8192 * 2));
    unsigned* W1pT = (unsigned*)(ws + alloc(6144 * 4));
    float* zbuf   = (float*)(ws + alloc(256 * 4));
    __hip_bfloat16* h1b   = (__hip_bfloat16*)(ws + alloc((size_t)NN * 64 * 2));
    __hip_bfloat16* web   = (__hip_bfloat16*)(ws + alloc((size_t)NT * 8 * 2));
    float* part   = (float*)(ws + alloc((size_t)NODEB * 3 * 4));
    (void)ws_size; (void)in_sizes; (void)n_in; (void)out_size;

    int nb_scan = (NN + 1023) / 1024;  // 98

    k_misc<<<MISCGRID, 256, 0, stream>>>(W2, a2s, a2d, wsd, W2pT, cnt, fill,
                                         tsw1, cw1, wB, W1, W1pT, zbuf);
    k_count<<<(NE + 255) / 256, 256, 0, stream>>>(dstE, cnt);
    k_scanA<<<nb_scan, 256, 0, stream>>>(cnt, rowptr, bsum);
    k_scanB<<<1, 64, 0, stream>>>(bsum, nb_scan);
    k_scanC<<<(NN + 255) / 256, 256, 0, stream>>>(bsum, rowptr);
    k_fill<<<(NT + 255) / 256, 256, 0, stream>>>(srcE, dstE, rowptr, fill, col, rowv);

    k_gemm1<<<NN / G1ROWS, 128, 0, stream>>>(x, W1pT, a1s, a1d, zbuf, h1b, aad1);
    k_edgew<<<(NT + 255) / 256, 256, 0, stream>>>(aad1, col, rowv, web);
    k_agg1<<<NN / 16, 256, 0, stream>>>(h1b, web, rowptr, col, b1, out1b);
    k_att2<<<NODEB, 256, 0, stream>>>(out1b, wsd, aad2);
    k_edgew<<<(NT + 255) / 256, 256, 0, stream>>>(aad2, col, rowv, web);

    k_l2f<<<NODEB, 256, 0, stream>>>(out1b, web, rowptr, col, W2pT, b2, wB,
                                     tsb1, cb1, tsw2, tsb2, cw2, cb2, tst, ctg, msk, part);

    k_final<<<1, 256, 0, stream>>>(part, (float*)d_out, NODEB);
}